// Round 1
// baseline (11770.061 us; speedup 1.0000x reference)
//
#include <hip/hip_runtime.h>

#define NN 100000
#define NE 600000
#define KE 3
#define NL 3
#define D  128
#define EPS 1e-5f

__device__ __forceinline__ void atomic_add_f32(float* p, float v) {
    unsafeAtomicAdd(p, v);   // HW global_atomic_add_f32 (no CAS loop)
}

// ---- degree ----
__global__ void deg_kernel(const int* __restrict__ dst, float* __restrict__ deg) {
    int i = blockIdx.x * blockDim.x + threadIdx.x;
    if (i < KE * NE) {
        int k = i / NE;
        atomic_add_f32(&deg[(size_t)k * NN + dst[i]], 1.0f);
    }
}
__global__ void invdeg_kernel(float* __restrict__ deg) {
    int i = blockIdx.x * blockDim.x + threadIdx.x;
    if (i < KE * NN) deg[i] = 1.0f / fmaxf(deg[i], 1.0f);
}

// ---- edge scatter: neigh[dst] += h[src], 32 threads/edge, float4 ----
__global__ void scatter_kernel(const float* __restrict__ h, const int* __restrict__ src,
                               const int* __restrict__ dst, float* __restrict__ neigh) {
    int gid = blockIdx.x * blockDim.x + threadIdx.x;
    int e = gid >> 5;
    if (e >= NE) return;
    int q = (gid & 31) << 2;
    int s = src[e], d = dst[e];
    const float4 v = *(const float4*)(h + (size_t)s * D + q);
    float* p = neigh + (size_t)d * D + q;
    atomic_add_f32(p + 0, v.x);
    atomic_add_f32(p + 1, v.y);
    atomic_add_f32(p + 2, v.z);
    atomic_add_f32(p + 3, v.w);
}

// ---- fused dual GEMM: acc(+)= relu?( h*Ws + (neigh*invdeg)*Wn + b ) ----
// 128 threads (col = tid), 32 rows per block. LDS 32KB.
__global__ void gemm_kernel(const float* __restrict__ h, const float* __restrict__ neigh,
                            const float* __restrict__ invdeg,
                            const float* __restrict__ Ws, const float* __restrict__ Wn,
                            const float* __restrict__ bias, float* __restrict__ acc,
                            int relu, int first) {
    __shared__ float hs[32][D];
    __shared__ float nb[32][D];
    const int c = threadIdx.x;
    const int row0 = blockIdx.x * 32;

    // stage 32x128 tiles, float4 per thread, 4 rows per pass
    #pragma unroll
    for (int pass = 0; pass < 8; ++pass) {
        int r  = pass * 4 + (threadIdx.x >> 5);
        int d4 = (threadIdx.x & 31) << 2;
        int row = row0 + r;
        float4 hv = *(const float4*)(h + (size_t)row * D + d4);
        float4 nv = *(const float4*)(neigh + (size_t)row * D + d4);
        float s = invdeg[row];
        nv.x *= s; nv.y *= s; nv.z *= s; nv.w *= s;
        *(float4*)&hs[r][d4] = hv;
        *(float4*)&nb[r][d4] = nv;
    }
    __syncthreads();

    float accr[32];
    #pragma unroll
    for (int r = 0; r < 32; ++r) accr[r] = 0.f;

    for (int dd = 0; dd < 32; ++dd) {
        const int d = dd * 4;
        float ws0 = Ws[(d + 0) * D + c], ws1 = Ws[(d + 1) * D + c];
        float ws2 = Ws[(d + 2) * D + c], ws3 = Ws[(d + 3) * D + c];
        float wn0 = Wn[(d + 0) * D + c], wn1 = Wn[(d + 1) * D + c];
        float wn2 = Wn[(d + 2) * D + c], wn3 = Wn[(d + 3) * D + c];
        #pragma unroll
        for (int r = 0; r < 32; ++r) {
            float4 hv = *(const float4*)&hs[r][d];
            float4 nv = *(const float4*)&nb[r][d];
            accr[r] += hv.x * ws0 + hv.y * ws1 + hv.z * ws2 + hv.w * ws3
                     + nv.x * wn0 + nv.y * wn1 + nv.z * wn2 + nv.w * wn3;
        }
    }

    const float bc = bias[c];
    for (int r = 0; r < 32; ++r) {
        float o = accr[r] + bc;
        if (relu) o = fmaxf(o, 0.f);
        size_t idx = (size_t)(row0 + r) * D + c;
        if (first) acc[idx] = o;
        else       acc[idx] += o;
    }
}

// ---- batchnorm stats: per-column sum & sumsq ----
__global__ void stats_kernel(const float* __restrict__ acc,
                             float* __restrict__ colsum, float* __restrict__ colsq) {
    const int c = threadIdx.x;  // 128
    float s = 0.f, s2 = 0.f;
    for (int r = blockIdx.x; r < NN; r += gridDim.x) {
        float v = acc[(size_t)r * D + c];
        s += v; s2 += v * v;
    }
    atomic_add_f32(&colsum[c], s);
    atomic_add_f32(&colsq[c], s2);
}

__global__ void finalize_kernel(const float* __restrict__ colsum, const float* __restrict__ colsq,
                                const float* __restrict__ gamma, const float* __restrict__ beta,
                                float* __restrict__ ss) {
    int c = threadIdx.x;  // 128
    float mu  = colsum[c] * (1.0f / NN);
    float var = colsq[c] * (1.0f / NN) - mu * mu;
    float sc  = gamma[c] * rsqrtf(var + EPS);
    ss[c]     = sc;
    ss[D + c] = beta[c] - mu * sc;
}

__global__ void bn_kernel(const float* __restrict__ acc, const float* __restrict__ ss,
                          float* __restrict__ out) {
    size_t i = (size_t)blockIdx.x * blockDim.x + threadIdx.x;
    if (i >= (size_t)NN * D / 4) return;
    int c4 = (int)(i & 31) << 2;
    float4 v  = *(const float4*)(acc + i * 4);
    float4 sc = *(const float4*)(ss + c4);
    float4 sh = *(const float4*)(ss + D + c4);
    float4 o;
    o.x = v.x * sc.x + sh.x;
    o.y = v.y * sc.y + sh.y;
    o.z = v.z * sc.z + sh.z;
    o.w = v.w * sc.w + sh.w;
    *(float4*)(out + i * 4) = o;
}

extern "C" void kernel_launch(void* const* d_in, const int* in_sizes, int n_in,
                              void* d_out, int out_size, void* d_ws, size_t ws_size,
                              hipStream_t stream) {
    const float* x       = (const float*)d_in[0];
    const int*   src     = (const int*)d_in[1];
    const int*   dst     = (const int*)d_in[2];
    const float* W_self  = (const float*)d_in[3];
    const float* W_neigh = (const float*)d_in[4];
    const float* bvec    = (const float*)d_in[5];
    const float* gamma   = (const float*)d_in[6];
    const float* beta    = (const float*)d_in[7];
    float* out = (float*)d_out;

    float* h      = (float*)d_ws;                       // N*D
    float* acc    = h + (size_t)NN * D;                 // N*D
    float* neigh  = acc + (size_t)NN * D;               // N*D
    float* invdeg = neigh + (size_t)NN * D;             // K*N
    float* colsum = invdeg + (size_t)KE * NN;           // D
    float* colsq  = colsum + D;                         // D
    float* ss     = colsq + D;                          // 2*D

    hipMemcpyAsync(h, x, sizeof(float) * (size_t)NN * D, hipMemcpyDeviceToDevice, stream);

    hipMemsetAsync(invdeg, 0, sizeof(float) * (size_t)KE * NN, stream);
    deg_kernel<<<(KE * NE + 255) / 256, 256, 0, stream>>>(dst, invdeg);
    invdeg_kernel<<<(KE * NN + 255) / 256, 256, 0, stream>>>(invdeg);

    for (int l = 0; l < NL; ++l) {
        int relu = (l < NL - 1) ? 1 : 0;
        for (int k = 0; k < KE; ++k) {
            hipMemsetAsync(neigh, 0, sizeof(float) * (size_t)NN * D, stream);
            scatter_kernel<<<(NE * 32 + 255) / 256, 256, 0, stream>>>(
                h, src + (size_t)k * NE, dst + (size_t)k * NE, neigh);
            gemm_kernel<<<NN / 32, 128, 0, stream>>>(
                h, neigh, invdeg + (size_t)k * NN,
                W_self + (size_t)(l * KE + k) * D * D,
                W_neigh + (size_t)(l * KE + k) * D * D,
                bvec + (size_t)(l * KE + k) * D,
                acc, relu, (k == 0) ? 1 : 0);
        }
        hipMemsetAsync(colsum, 0, sizeof(float) * 2 * D, stream);
        stats_kernel<<<512, 128, 0, stream>>>(acc, colsum, colsq);
        finalize_kernel<<<1, 128, 0, stream>>>(colsum, colsq, gamma + (size_t)l * D,
                                               beta + (size_t)l * D, ss);
        float* dest = (l == NL - 1) ? out : h;
        bn_kernel<<<((size_t)NN * D / 4 + 255) / 256, 256, 0, stream>>>(acc, ss, dest);
    }
}

// Round 2
// 3297.051 us; speedup vs baseline: 3.5699x; 3.5699x over previous
//
#include <hip/hip_runtime.h>

#define NN 100000
#define NE 600000
#define KE 3
#define NL 3
#define D  128
#define EPS 1e-5f

__device__ __forceinline__ void atomic_add_f32(float* p, float v) {
    unsafeAtomicAdd(p, v);
}

// ---- int in-degree per etype ----
__global__ void degi_kernel(const int* __restrict__ dst, int* __restrict__ degi) {
    int i = blockIdx.x * blockDim.x + threadIdx.x;
    if (i < KE * NE) {
        int k = i / NE;
        atomicAdd(&degi[(size_t)k * NN + dst[i]], 1);
    }
}

__global__ void invdeg_kernel(const int* __restrict__ degi, float* __restrict__ invdeg) {
    int i = blockIdx.x * blockDim.x + threadIdx.x;
    if (i < KE * NN) invdeg[i] = 1.0f / (float)max(degi[i], 1);
}

// ---- per-etype exclusive scan of degrees -> rowptr ----
__global__ void scan_kernel(const int* __restrict__ degi, int* __restrict__ rowptr) {
    const int k = blockIdx.x;
    const int* d = degi + (size_t)k * NN;
    int* rp = rowptr + (size_t)k * (NN + 1);
    const int C = (NN + 1023) / 1024;  // 98
    const int t = threadIdx.x;
    const int i0 = t * C, i1 = min(i0 + C, NN);
    int sum = 0;
    for (int i = i0; i < i1; ++i) sum += d[i];
    __shared__ int sd[1024];
    sd[t] = sum;
    __syncthreads();
    for (int off = 1; off < 1024; off <<= 1) {
        int v = (t >= off) ? sd[t - off] : 0;
        __syncthreads();
        sd[t] += v;
        __syncthreads();
    }
    int run = sd[t] - sum;  // exclusive prefix
    for (int i = i0; i < i1; ++i) { rp[i] = run; run += d[i]; }
    if (t == 0) rp[NN] = NE;
}

__global__ void cursor_init_kernel(const int* __restrict__ rowptr, int* __restrict__ cursor) {
    int i = blockIdx.x * blockDim.x + threadIdx.x;
    if (i < KE * NN) {
        int k = i / NN, n = i - k * NN;
        cursor[i] = rowptr[(size_t)k * (NN + 1) + n];
    }
}

__global__ void fill_kernel(const int* __restrict__ src, const int* __restrict__ dst,
                            int* __restrict__ cursor, int* __restrict__ csr) {
    int i = blockIdx.x * blockDim.x + threadIdx.x;
    if (i < KE * NE) {
        int k = i / NE;
        int p = atomicAdd(&cursor[(size_t)k * NN + dst[i]], 1);
        csr[(size_t)k * NE + p] = src[i];
    }
}

// ---- gather aggregation: neigh[n] = invdeg[n] * sum_{e in in(n)} h[src[e]] ----
// 32 lanes per node (each lane owns a float4 of D), 8 nodes per 256-thread block.
__global__ void gather_kernel(const float* __restrict__ h, const int* __restrict__ csr,
                              const int* __restrict__ rowptr, const float* __restrict__ invdeg,
                              float* __restrict__ neigh) {
    int node = blockIdx.x * 8 + (threadIdx.x >> 5);
    if (node >= NN) return;
    const int q = (threadIdx.x & 31) << 2;
    const int beg = rowptr[node], end = rowptr[node + 1];
    float4 v = {0.f, 0.f, 0.f, 0.f};
    int j = beg;
    int s = (j < end) ? csr[j] : 0;
    while (j < end) {
        int snext = (j + 1 < end) ? csr[j + 1] : 0;
        float4 t = *(const float4*)(h + (size_t)s * D + q);
        v.x += t.x; v.y += t.y; v.z += t.z; v.w += t.w;
        s = snext;
        ++j;
    }
    float sc = invdeg[node];
    v.x *= sc; v.y *= sc; v.z *= sc; v.w *= sc;
    *(float4*)(neigh + (size_t)node * D + q) = v;
}

// ---- fused dual GEMM: acc(+)= relu?( h*Ws + neigh*Wn + b ) ----
__global__ void gemm_kernel(const float* __restrict__ h, const float* __restrict__ neigh,
                            const float* __restrict__ Ws, const float* __restrict__ Wn,
                            const float* __restrict__ bias, float* __restrict__ acc,
                            int relu, int first) {
    __shared__ float hs[32][D];
    __shared__ float nb[32][D];
    const int c = threadIdx.x;
    const int row0 = blockIdx.x * 32;

    #pragma unroll
    for (int pass = 0; pass < 8; ++pass) {
        int r  = pass * 4 + (threadIdx.x >> 5);
        int d4 = (threadIdx.x & 31) << 2;
        int row = row0 + r;
        *(float4*)&hs[r][d4] = *(const float4*)(h + (size_t)row * D + d4);
        *(float4*)&nb[r][d4] = *(const float4*)(neigh + (size_t)row * D + d4);
    }
    __syncthreads();

    float accr[32];
    #pragma unroll
    for (int r = 0; r < 32; ++r) accr[r] = 0.f;

    for (int dd = 0; dd < 32; ++dd) {
        const int d = dd * 4;
        float ws0 = Ws[(d + 0) * D + c], ws1 = Ws[(d + 1) * D + c];
        float ws2 = Ws[(d + 2) * D + c], ws3 = Ws[(d + 3) * D + c];
        float wn0 = Wn[(d + 0) * D + c], wn1 = Wn[(d + 1) * D + c];
        float wn2 = Wn[(d + 2) * D + c], wn3 = Wn[(d + 3) * D + c];
        #pragma unroll
        for (int r = 0; r < 32; ++r) {
            float4 hv = *(const float4*)&hs[r][d];
            float4 nv = *(const float4*)&nb[r][d];
            accr[r] += hv.x * ws0 + hv.y * ws1 + hv.z * ws2 + hv.w * ws3
                     + nv.x * wn0 + nv.y * wn1 + nv.z * wn2 + nv.w * wn3;
        }
    }

    const float bc = bias[c];
    for (int r = 0; r < 32; ++r) {
        float o = accr[r] + bc;
        if (relu) o = fmaxf(o, 0.f);
        size_t idx = (size_t)(row0 + r) * D + c;
        if (first) acc[idx] = o;
        else       acc[idx] += o;
    }
}

// ---- batchnorm ----
__global__ void stats_kernel(const float* __restrict__ acc,
                             float* __restrict__ colsum, float* __restrict__ colsq) {
    const int c = threadIdx.x;  // 128
    float s = 0.f, s2 = 0.f;
    for (int r = blockIdx.x; r < NN; r += gridDim.x) {
        float v = acc[(size_t)r * D + c];
        s += v; s2 += v * v;
    }
    atomic_add_f32(&colsum[c], s);
    atomic_add_f32(&colsq[c], s2);
}

__global__ void finalize_kernel(const float* __restrict__ colsum, const float* __restrict__ colsq,
                                const float* __restrict__ gamma, const float* __restrict__ beta,
                                float* __restrict__ ss) {
    int c = threadIdx.x;  // 128
    float mu  = colsum[c] * (1.0f / NN);
    float var = colsq[c] * (1.0f / NN) - mu * mu;
    float sc  = gamma[c] * rsqrtf(var + EPS);
    ss[c]     = sc;
    ss[D + c] = beta[c] - mu * sc;
}

__global__ void bn_kernel(const float* __restrict__ acc, const float* __restrict__ ss,
                          float* __restrict__ out) {
    size_t i = (size_t)blockIdx.x * blockDim.x + threadIdx.x;
    if (i >= (size_t)NN * D / 4) return;
    int c4 = (int)(i & 31) << 2;
    float4 v  = *(const float4*)(acc + i * 4);
    float4 sc = *(const float4*)(ss + c4);
    float4 sh = *(const float4*)(ss + D + c4);
    float4 o;
    o.x = v.x * sc.x + sh.x;
    o.y = v.y * sc.y + sh.y;
    o.z = v.z * sc.z + sh.z;
    o.w = v.w * sc.w + sh.w;
    *(float4*)(out + i * 4) = o;
}

extern "C" void kernel_launch(void* const* d_in, const int* in_sizes, int n_in,
                              void* d_out, int out_size, void* d_ws, size_t ws_size,
                              hipStream_t stream) {
    const float* x       = (const float*)d_in[0];
    const int*   src     = (const int*)d_in[1];
    const int*   dst     = (const int*)d_in[2];
    const float* W_self  = (const float*)d_in[3];
    const float* W_neigh = (const float*)d_in[4];
    const float* bvec    = (const float*)d_in[5];
    const float* gamma   = (const float*)d_in[6];
    const float* beta    = (const float*)d_in[7];
    float* out = (float*)d_out;

    // workspace layout (floats first, then ints)
    float* h      = (float*)d_ws;                       // N*D
    float* acc    = h + (size_t)NN * D;                 // N*D
    float* neigh  = acc + (size_t)NN * D;               // N*D
    float* invdeg = neigh + (size_t)NN * D;             // K*N
    float* colsum = invdeg + (size_t)KE * NN;           // D
    float* colsq  = colsum + D;                         // D
    float* ss     = colsq + D;                          // 2*D
    int*   degi   = (int*)(ss + 2 * D);                 // K*N
    int*   rowptr = degi + (size_t)KE * NN;             // K*(N+1)
    int*   cursor = rowptr + (size_t)KE * (NN + 1);     // K*N
    int*   csr    = cursor + (size_t)KE * NN;           // K*E

    hipMemcpyAsync(h, x, sizeof(float) * (size_t)NN * D, hipMemcpyDeviceToDevice, stream);

    // ---- CSR build (once) ----
    hipMemsetAsync(degi, 0, sizeof(int) * (size_t)KE * NN, stream);
    degi_kernel<<<(KE * NE + 255) / 256, 256, 0, stream>>>(dst, degi);
    invdeg_kernel<<<(KE * NN + 255) / 256, 256, 0, stream>>>(degi, invdeg);
    scan_kernel<<<KE, 1024, 0, stream>>>(degi, rowptr);
    cursor_init_kernel<<<(KE * NN + 255) / 256, 256, 0, stream>>>(rowptr, cursor);
    fill_kernel<<<(KE * NE + 255) / 256, 256, 0, stream>>>(src, dst, cursor, csr);

    for (int l = 0; l < NL; ++l) {
        int relu = (l < NL - 1) ? 1 : 0;
        for (int k = 0; k < KE; ++k) {
            gather_kernel<<<(NN + 7) / 8, 256, 0, stream>>>(
                h, csr + (size_t)k * NE, rowptr + (size_t)k * (NN + 1),
                invdeg + (size_t)k * NN, neigh);
            gemm_kernel<<<NN / 32, 128, 0, stream>>>(
                h, neigh,
                W_self + (size_t)(l * KE + k) * D * D,
                W_neigh + (size_t)(l * KE + k) * D * D,
                bvec + (size_t)(l * KE + k) * D,
                acc, relu, (k == 0) ? 1 : 0);
        }
        hipMemsetAsync(colsum, 0, sizeof(float) * 2 * D, stream);
        stats_kernel<<<512, 128, 0, stream>>>(acc, colsum, colsq);
        finalize_kernel<<<1, 128, 0, stream>>>(colsum, colsq, gamma + (size_t)l * D,
                                               beta + (size_t)l * D, ss);
        float* dest = (l == NL - 1) ? out : h;
        bn_kernel<<<((size_t)NN * D / 4 + 255) / 256, 256, 0, stream>>>(acc, ss, dest);
    }
}

// Round 3
// 1093.938 us; speedup vs baseline: 10.7594x; 3.0139x over previous
//
#include <hip/hip_runtime.h>

#define NN 100000
#define NNP 100096   // NN padded to multiple of 128 (GEMM tail reads)
#define NE 600000
#define KE 3
#define NL 3
#define D  128
#define EPS 1e-5f

typedef __attribute__((ext_vector_type(8))) short short8;
typedef __attribute__((ext_vector_type(4))) float floatx4;

__device__ __forceinline__ void atomic_add_f32(float* p, float v) { unsafeAtomicAdd(p, v); }

__device__ __forceinline__ float bf2f(unsigned int u16) {
    unsigned int v = u16 << 16;
    return __builtin_bit_cast(float, v);
}
__device__ __forceinline__ unsigned int f2bf(float f) {   // RNE
    unsigned int u = __builtin_bit_cast(unsigned int, f);
    u += 0x7FFFu + ((u >> 16) & 1u);
    return u >> 16;
}
__device__ __forceinline__ unsigned int pack2(float a, float b) {
    return f2bf(a) | (f2bf(b) << 16);
}

// ---- x (fp32) -> h (bf16) ----
__global__ void convert_x_kernel(const float* __restrict__ x, ushort* __restrict__ hbf) {
    size_t i = (size_t)blockIdx.x * blockDim.x + threadIdx.x;   // one per 4 elems
    if (i >= (size_t)NN * D / 4) return;
    float4 v = *(const float4*)(x + i * 4);
    uint2 o;
    o.x = pack2(v.x, v.y);
    o.y = pack2(v.z, v.w);
    *(uint2*)(hbf + i * 4) = o;
}

// ---- W prep: Bt[l,k][n][kk] bf16, kk<128 -> Ws[kk][n], else Wn[kk-128][n] ----
__global__ void wprep_kernel(const float* __restrict__ Ws, const float* __restrict__ Wn,
                             ushort* __restrict__ Bt) {
    int idx = blockIdx.x * blockDim.x + threadIdx.x;
    if (idx >= NL * KE * 128 * 256) return;
    int lk  = idx >> 15;            // /(128*256)
    int rem = idx & 32767;
    int n   = rem >> 8;
    int kk  = rem & 255;
    float v = (kk < 128) ? Ws[(size_t)lk * 16384 + kk * 128 + n]
                         : Wn[(size_t)lk * 16384 + (kk - 128) * 128 + n];
    Bt[idx] = (ushort)f2bf(v);
}

// ---- CSR build ----
__global__ void degi_kernel(const int* __restrict__ dst, int* __restrict__ degi) {
    int i = blockIdx.x * blockDim.x + threadIdx.x;
    if (i < KE * NE) {
        int k = i / NE;
        atomicAdd(&degi[(size_t)k * NN + dst[i]], 1);
    }
}
__global__ void invdeg_kernel(const int* __restrict__ degi, float* __restrict__ invdeg) {
    int i = blockIdx.x * blockDim.x + threadIdx.x;
    if (i < KE * NN) invdeg[i] = 1.0f / (float)max(degi[i], 1);
}
__global__ void scan_kernel(const int* __restrict__ degi, int* __restrict__ rowptr) {
    const int k = blockIdx.x;
    const int* d = degi + (size_t)k * NN;
    int* rp = rowptr + (size_t)k * (NN + 1);
    const int C = (NN + 1023) / 1024;
    const int t = threadIdx.x;
    const int i0 = t * C, i1 = min(i0 + C, NN);
    int sum = 0;
    for (int i = i0; i < i1; ++i) sum += d[i];
    __shared__ int sd[1024];
    sd[t] = sum;
    __syncthreads();
    for (int off = 1; off < 1024; off <<= 1) {
        int v = (t >= off) ? sd[t - off] : 0;
        __syncthreads();
        sd[t] += v;
        __syncthreads();
    }
    int run = sd[t] - sum;
    for (int i = i0; i < i1; ++i) { rp[i] = run; run += d[i]; }
    if (t == 0) rp[NN] = NE;
}
__global__ void cursor_init_kernel(const int* __restrict__ rowptr, int* __restrict__ cursor) {
    int i = blockIdx.x * blockDim.x + threadIdx.x;
    if (i < KE * NN) {
        int k = i / NN, n = i - k * NN;
        cursor[i] = rowptr[(size_t)k * (NN + 1) + n];
    }
}
__global__ void fill_kernel(const int* __restrict__ src, const int* __restrict__ dst,
                            int* __restrict__ cursor, int* __restrict__ csr) {
    int i = blockIdx.x * blockDim.x + threadIdx.x;
    if (i < KE * NE) {
        int k = i / NE;
        int p = atomicAdd(&cursor[(size_t)k * NN + dst[i]], 1);
        csr[(size_t)k * NE + p] = src[i];
    }
}

// ---- gather (all 3 etypes): neigh[k][n] = invdeg * sum h[src] , bf16 in/out ----
// 16 lanes per node, 16B (8 bf16) per lane.
__global__ void gather3_kernel(const ushort* __restrict__ hbf, const int* __restrict__ csr,
                               const int* __restrict__ rowptr, const float* __restrict__ invdeg,
                               ushort* __restrict__ neigh) {
    int g = blockIdx.x * 16 + (threadIdx.x >> 4);
    if (g >= KE * NN) return;
    int k = g / NN, node = g - k * NN;
    const int q = (threadIdx.x & 15) * 8;
    const int* rp = rowptr + (size_t)k * (NN + 1) + node;
    const int* cs = csr + (size_t)k * NE;
    int beg = rp[0], end = rp[1];
    float f0=0,f1=0,f2=0,f3=0,f4=0,f5=0,f6=0,f7=0;
    for (int j = beg; j < end; ++j) {
        int s = cs[j];
        uint4 v = *(const uint4*)(hbf + (size_t)s * D + q);
        f0 += bf2f(v.x & 0xffff); f1 += bf2f(v.x >> 16);
        f2 += bf2f(v.y & 0xffff); f3 += bf2f(v.y >> 16);
        f4 += bf2f(v.z & 0xffff); f5 += bf2f(v.z >> 16);
        f6 += bf2f(v.w & 0xffff); f7 += bf2f(v.w >> 16);
    }
    float sc = invdeg[g];
    uint4 o;
    o.x = pack2(f0 * sc, f1 * sc);
    o.y = pack2(f2 * sc, f3 * sc);
    o.z = pack2(f4 * sc, f5 * sc);
    o.w = pack2(f6 * sc, f7 * sc);
    *(uint4*)(neigh + (size_t)k * NNP * D + (size_t)node * D + q) = o;
}

// ---- fused layer GEMM: acc = sum_k maybe_relu( [h|neigh_k] @ Bt_k + b_k ) ----
// 128x128 M-tile, 256 threads = 4 waves (2x2 of 64x64), mfma 16x16x32 bf16.
__global__ __launch_bounds__(256, 2)
void layer_gemm_kernel(const ushort* __restrict__ hbf, const ushort* __restrict__ neigh,
                       const ushort* __restrict__ Bt,   // [KE][128][256] this layer
                       const float* __restrict__ bias,  // [KE][D] this layer
                       float* __restrict__ acc, int relu) {
    __shared__ __align__(16) ushort As[128][72];  // padded: 144B stride = 9x16B
    __shared__ __align__(16) ushort Bs[128][72];
    const int tid  = threadIdx.x;
    const int wave = tid >> 6, lane = tid & 63;
    const int wm = wave & 1, wn = wave >> 1;
    const int lrow = lane & 15, quad = lane >> 4;
    const int m0 = blockIdx.x * 128;
    const int ldrow = tid >> 3;        // 0..31
    const int ldcol = (tid & 7) * 8;   // 0,8,..,56

    floatx4 tot[4][4];
    #pragma unroll
    for (int a = 0; a < 4; ++a)
        #pragma unroll
        for (int b = 0; b < 4; ++b)
            tot[a][b] = (floatx4){0.f, 0.f, 0.f, 0.f};

    for (int k = 0; k < KE; ++k) {
        floatx4 o[4][4];
        #pragma unroll
        for (int a = 0; a < 4; ++a)
            #pragma unroll
            for (int b = 0; b < 4; ++b)
                o[a][b] = (floatx4){0.f, 0.f, 0.f, 0.f};

        for (int part = 0; part < 2; ++part) {
            const ushort* Asrc = part ? (neigh + (size_t)k * NNP * D) : hbf;
            #pragma unroll
            for (int kc = 0; kc < 2; ++kc) {
                __syncthreads();
                const int kbase = kc * 64;
                #pragma unroll
                for (int p = 0; p < 4; ++p) {
                    int r = p * 32 + ldrow;
                    uint4 v = *(const uint4*)(Asrc + (size_t)(m0 + r) * D + kbase + ldcol);
                    *(uint4*)(&As[r][ldcol]) = v;
                }
                const ushort* Bsrc = Bt + (size_t)k * 128 * 256 + part * 128 + kbase;
                #pragma unroll
                for (int p = 0; p < 4; ++p) {
                    int n = p * 32 + ldrow;
                    uint4 v = *(const uint4*)(Bsrc + (size_t)n * 256 + ldcol);
                    *(uint4*)(&Bs[n][ldcol]) = v;
                }
                __syncthreads();
                #pragma unroll
                for (int ks = 0; ks < 2; ++ks) {
                    short8 af[4], bfr[4];
                    const int koff = ks * 32 + quad * 8;
                    #pragma unroll
                    for (int im = 0; im < 4; ++im)
                        af[im] = *(const short8*)(&As[wm * 64 + im * 16 + lrow][koff]);
                    #pragma unroll
                    for (int in = 0; in < 4; ++in)
                        bfr[in] = *(const short8*)(&Bs[wn * 64 + in * 16 + lrow][koff]);
                    #pragma unroll
                    for (int im = 0; im < 4; ++im)
                        #pragma unroll
                        for (int in = 0; in < 4; ++in)
                            o[im][in] = __builtin_amdgcn_mfma_f32_16x16x32_bf16(
                                af[im], bfr[in], o[im][in], 0, 0, 0);
                }
            }
        }
        // per-etype epilogue: +bias, relu, accumulate
        const float* bk = bias + k * D;
        float bv[4];
        #pragma unroll
        for (int in = 0; in < 4; ++in) bv[in] = bk[wn * 64 + in * 16 + lrow];
        #pragma unroll
        for (int im = 0; im < 4; ++im)
            #pragma unroll
            for (int in = 0; in < 4; ++in)
                #pragma unroll
                for (int r = 0; r < 4; ++r) {
                    float v = o[im][in][r] + bv[in];
                    if (relu) v = fmaxf(v, 0.f);
                    tot[im][in][r] += v;
                }
    }
    // store: row = m0 + wm*64 + im*16 + quad*4 + r ; col = wn*64 + in*16 + lrow
    #pragma unroll
    for (int im = 0; im < 4; ++im)
        #pragma unroll
        for (int r = 0; r < 4; ++r) {
            int row = m0 + wm * 64 + im * 16 + quad * 4 + r;
            if (row < NN) {
                #pragma unroll
                for (int in = 0; in < 4; ++in)
                    acc[(size_t)row * D + wn * 64 + in * 16 + lrow] = tot[im][in][r];
            }
        }
}

// ---- batchnorm ----
__global__ void stats_kernel(const float* __restrict__ acc,
                             float* __restrict__ colsum, float* __restrict__ colsq) {
    const int c = threadIdx.x;  // 128
    float s = 0.f, s2 = 0.f;
    for (int r = blockIdx.x; r < NN; r += gridDim.x) {
        float v = acc[(size_t)r * D + c];
        s += v; s2 += v * v;
    }
    atomic_add_f32(&colsum[c], s);
    atomic_add_f32(&colsq[c], s2);
}
__global__ void finalize_kernel(const float* __restrict__ colsum, const float* __restrict__ colsq,
                                const float* __restrict__ gamma, const float* __restrict__ beta,
                                float* __restrict__ ss) {
    int c = threadIdx.x;  // 128
    float mu  = colsum[c] * (1.0f / NN);
    float var = colsq[c] * (1.0f / NN) - mu * mu;
    float sc  = gamma[c] * rsqrtf(var + EPS);
    ss[c]     = sc;
    ss[D + c] = beta[c] - mu * sc;
}
// normalize; last layer -> fp32 out, else -> bf16 h
__global__ void bn_kernel(const float* __restrict__ acc, const float* __restrict__ ss,
                          ushort* __restrict__ hbf, float* __restrict__ out, int last) {
    size_t i = (size_t)blockIdx.x * blockDim.x + threadIdx.x;
    if (i >= (size_t)NN * D / 4) return;
    int c4 = (int)(i & 31) << 2;
    float4 v  = *(const float4*)(acc + i * 4);
    float4 sc = *(const float4*)(ss + c4);
    float4 sh = *(const float4*)(ss + D + c4);
    float4 o;
    o.x = v.x * sc.x + sh.x;
    o.y = v.y * sc.y + sh.y;
    o.z = v.z * sc.z + sh.z;
    o.w = v.w * sc.w + sh.w;
    if (last) {
        *(float4*)(out + i * 4) = o;
    } else {
        uint2 p;
        p.x = pack2(o.x, o.y);
        p.y = pack2(o.z, o.w);
        *(uint2*)(hbf + i * 4) = p;
    }
}

extern "C" void kernel_launch(void* const* d_in, const int* in_sizes, int n_in,
                              void* d_out, int out_size, void* d_ws, size_t ws_size,
                              hipStream_t stream) {
    const float* x       = (const float*)d_in[0];
    const int*   src     = (const int*)d_in[1];
    const int*   dst     = (const int*)d_in[2];
    const float* W_self  = (const float*)d_in[3];
    const float* W_neigh = (const float*)d_in[4];
    const float* bvec    = (const float*)d_in[5];
    const float* gamma   = (const float*)d_in[6];
    const float* beta    = (const float*)d_in[7];
    float* out = (float*)d_out;

    // ---- workspace layout ----
    float*  acc    = (float*)d_ws;                        // NN*D fp32
    float*  invdeg = acc + (size_t)NN * D;                // KE*NN
    float*  colsum = invdeg + (size_t)KE * NN;            // D
    float*  colsq  = colsum + D;                          // D
    float*  ss     = colsq + D;                           // 2*D
    ushort* hbf    = (ushort*)(ss + 2 * D);               // NNP*D bf16
    ushort* neigh  = hbf + (size_t)NNP * D;               // KE*NNP*D bf16
    ushort* Btw    = neigh + (size_t)KE * NNP * D;        // NL*KE*128*256 bf16
    int*    degi   = (int*)(Btw + (size_t)NL * KE * 128 * 256);  // KE*NN
    int*    rowptr = degi + (size_t)KE * NN;              // KE*(NN+1)
    int*    cursor = rowptr + (size_t)KE * (NN + 1);      // KE*NN
    int*    csr    = cursor + (size_t)KE * NN;            // KE*NE

    convert_x_kernel<<<(int)(((size_t)NN * D / 4 + 255) / 256), 256, 0, stream>>>(x, hbf);
    wprep_kernel<<<(NL * KE * 128 * 256 + 255) / 256, 256, 0, stream>>>(W_self, W_neigh, Btw);

    hipMemsetAsync(degi, 0, sizeof(int) * (size_t)KE * NN, stream);
    degi_kernel<<<(KE * NE + 255) / 256, 256, 0, stream>>>(dst, degi);
    invdeg_kernel<<<(KE * NN + 255) / 256, 256, 0, stream>>>(degi, invdeg);
    scan_kernel<<<KE, 1024, 0, stream>>>(degi, rowptr);
    cursor_init_kernel<<<(KE * NN + 255) / 256, 256, 0, stream>>>(rowptr, cursor);
    fill_kernel<<<(KE * NE + 255) / 256, 256, 0, stream>>>(src, dst, cursor, csr);

    for (int l = 0; l < NL; ++l) {
        int relu = (l < NL - 1) ? 1 : 0;
        gather3_kernel<<<(KE * NN + 15) / 16, 256, 0, stream>>>(hbf, csr, rowptr, invdeg, neigh);
        layer_gemm_kernel<<<NNP / 128, 256, 0, stream>>>(
            hbf, neigh,
            Btw + (size_t)l * KE * 128 * 256,
            bvec + (size_t)l * KE * D,
            acc, relu);
        hipMemsetAsync(colsum, 0, sizeof(float) * 2 * D, stream);
        stats_kernel<<<512, 128, 0, stream>>>(acc, colsum, colsq);
        finalize_kernel<<<1, 128, 0, stream>>>(colsum, colsq, gamma + (size_t)l * D,
                                               beta + (size_t)l * D, ss);
        bn_kernel<<<(int)(((size_t)NN * D / 4 + 255) / 256), 256, 0, stream>>>(
            acc, ss, hbf, out, (l == NL - 1) ? 1 : 0);
    }
}

// Round 4
// 908.469 us; speedup vs baseline: 12.9559x; 1.2042x over previous
//
#include <hip/hip_runtime.h>

#define NN 100000
#define NNP 100096   // NN padded to multiple of 128 (GEMM tail reads)
#define NE 600000
#define KE 3
#define NL 3
#define D  128
#define EPS 1e-5f
#define NB 391       // ceil(NN/256) blocks per etype for the scan

typedef __attribute__((ext_vector_type(8))) short short8;
typedef __attribute__((ext_vector_type(4))) float floatx4;

__device__ __forceinline__ void atomic_add_f32(float* p, float v) { unsafeAtomicAdd(p, v); }

__device__ __forceinline__ float bf2f(unsigned int u16) {
    unsigned int v = u16 << 16;
    return __builtin_bit_cast(float, v);
}
__device__ __forceinline__ unsigned int f2bf(float f) {   // RNE
    unsigned int u = __builtin_bit_cast(unsigned int, f);
    u += 0x7FFFu + ((u >> 16) & 1u);
    return u >> 16;
}
__device__ __forceinline__ unsigned int pack2(float a, float b) {
    return f2bf(a) | (f2bf(b) << 16);
}

// ---- x (fp32) -> h (bf16) ----
__global__ void convert_x_kernel(const float* __restrict__ x, ushort* __restrict__ hbf) {
    size_t i = (size_t)blockIdx.x * blockDim.x + threadIdx.x;
    if (i >= (size_t)NN * D / 4) return;
    float4 v = *(const float4*)(x + i * 4);
    uint2 o;
    o.x = pack2(v.x, v.y);
    o.y = pack2(v.z, v.w);
    *(uint2*)(hbf + i * 4) = o;
}

// ---- W prep: Bt[l,k][n][kk] bf16 ----
__global__ void wprep_kernel(const float* __restrict__ Ws, const float* __restrict__ Wn,
                             ushort* __restrict__ Bt) {
    int idx = blockIdx.x * blockDim.x + threadIdx.x;
    if (idx >= NL * KE * 128 * 256) return;
    int lk  = idx >> 15;
    int rem = idx & 32767;
    int n   = rem >> 8;
    int kk  = rem & 255;
    float v = (kk < 128) ? Ws[(size_t)lk * 16384 + kk * 128 + n]
                         : Wn[(size_t)lk * 16384 + (kk - 128) * 128 + n];
    Bt[idx] = (ushort)f2bf(v);
}

// ---- CSR build ----
__global__ void degi_kernel(const int* __restrict__ dst, int* __restrict__ degi) {
    int i = blockIdx.x * blockDim.x + threadIdx.x;
    if (i < KE * NE) {
        int k = i / NE;
        atomicAdd(&degi[(size_t)k * NN + dst[i]], 1);
    }
}

// phase A: per-256-chunk sums
__global__ void scan_a_kernel(const int* __restrict__ degi, int* __restrict__ bsum) {
    const int b = blockIdx.x;            // k*NB + lb
    const int k = b / NB, lb = b - k * NB;
    const int t = threadIdx.x;
    const int i = lb * 256 + t;
    int deg = (i < NN) ? degi[(size_t)k * NN + i] : 0;
    __shared__ int sd[256];
    sd[t] = deg;
    __syncthreads();
    for (int off = 128; off > 0; off >>= 1) {
        if (t < off) sd[t] += sd[t + off];
        __syncthreads();
    }
    if (t == 0) bsum[b] = sd[0];
}

// phase B: per-etype exclusive scan of NB block sums (512 threads >= NB)
__global__ void scan_b_kernel(int* __restrict__ bsum) {
    const int k = blockIdx.x;
    const int t = threadIdx.x;          // 512
    int v = (t < NB) ? bsum[k * NB + t] : 0;
    __shared__ int sd[512];
    sd[t] = v;
    __syncthreads();
    for (int off = 1; off < 512; off <<= 1) {
        int u = (t >= off) ? sd[t - off] : 0;
        __syncthreads();
        sd[t] += u;
        __syncthreads();
    }
    if (t < NB) bsum[k * NB + t] = sd[t] - v;   // exclusive
}

// phase C: intra-chunk exclusive scan + offset -> rowptr, cursor, invdeg
__global__ void scan_c_kernel(const int* __restrict__ degi, const int* __restrict__ bsum,
                              int* __restrict__ rowptr, int* __restrict__ cursor,
                              float* __restrict__ invdeg) {
    const int b = blockIdx.x;
    const int k = b / NB, lb = b - k * NB;
    const int t = threadIdx.x;
    const int i = lb * 256 + t;
    int deg = (i < NN) ? degi[(size_t)k * NN + i] : 0;
    __shared__ int sd[256];
    sd[t] = deg;
    __syncthreads();
    for (int off = 1; off < 256; off <<= 1) {
        int u = (t >= off) ? sd[t - off] : 0;
        __syncthreads();
        sd[t] += u;
        __syncthreads();
    }
    int val = bsum[b] + sd[t] - deg;   // exclusive global prefix
    if (i < NN) {
        rowptr[(size_t)k * (NN + 1) + i] = val;
        cursor[(size_t)k * NN + i] = val;
        invdeg[(size_t)k * NN + i] = 1.0f / (float)max(deg, 1);
    }
    if (i == NN) rowptr[(size_t)k * (NN + 1) + NN] = NE;
}

__global__ void fill_kernel(const int* __restrict__ src, const int* __restrict__ dst,
                            int* __restrict__ cursor, int* __restrict__ csr) {
    int i = blockIdx.x * blockDim.x + threadIdx.x;
    if (i < KE * NE) {
        int k = i / NE;
        int p = atomicAdd(&cursor[(size_t)k * NN + dst[i]], 1);
        csr[(size_t)k * NE + p] = src[i];
    }
}

// ---- gather (all 3 etypes), 16 lanes/node, 2 edges in flight ----
__global__ void gather3_kernel(const ushort* __restrict__ hbf, const int* __restrict__ csr,
                               const int* __restrict__ rowptr, const float* __restrict__ invdeg,
                               ushort* __restrict__ neigh) {
    int g = blockIdx.x * 16 + (threadIdx.x >> 4);
    if (g >= KE * NN) return;
    int k = g / NN, node = g - k * NN;
    const int q = (threadIdx.x & 15) * 8;
    const int* rp = rowptr + (size_t)k * (NN + 1) + node;
    const int* cs = csr + (size_t)k * NE;
    int beg = rp[0], end = rp[1];
    float f0=0,f1=0,f2=0,f3=0,f4=0,f5=0,f6=0,f7=0;
    int j = beg;
    for (; j + 2 <= end; j += 2) {
        int s0 = cs[j], s1 = cs[j + 1];
        uint4 a = *(const uint4*)(hbf + (size_t)s0 * D + q);
        uint4 b = *(const uint4*)(hbf + (size_t)s1 * D + q);
        f0 += bf2f(a.x & 0xffff) + bf2f(b.x & 0xffff);
        f1 += bf2f(a.x >> 16)    + bf2f(b.x >> 16);
        f2 += bf2f(a.y & 0xffff) + bf2f(b.y & 0xffff);
        f3 += bf2f(a.y >> 16)    + bf2f(b.y >> 16);
        f4 += bf2f(a.z & 0xffff) + bf2f(b.z & 0xffff);
        f5 += bf2f(a.z >> 16)    + bf2f(b.z >> 16);
        f6 += bf2f(a.w & 0xffff) + bf2f(b.w & 0xffff);
        f7 += bf2f(a.w >> 16)    + bf2f(b.w >> 16);
    }
    if (j < end) {
        int s0 = cs[j];
        uint4 a = *(const uint4*)(hbf + (size_t)s0 * D + q);
        f0 += bf2f(a.x & 0xffff); f1 += bf2f(a.x >> 16);
        f2 += bf2f(a.y & 0xffff); f3 += bf2f(a.y >> 16);
        f4 += bf2f(a.z & 0xffff); f5 += bf2f(a.z >> 16);
        f6 += bf2f(a.w & 0xffff); f7 += bf2f(a.w >> 16);
    }
    float sc = invdeg[g];
    uint4 o;
    o.x = pack2(f0 * sc, f1 * sc);
    o.y = pack2(f2 * sc, f3 * sc);
    o.z = pack2(f4 * sc, f5 * sc);
    o.w = pack2(f6 * sc, f7 * sc);
    *(uint4*)(neigh + (size_t)k * NNP * D + (size_t)node * D + q) = o;
}

// ---- fused layer GEMM ----
__global__ __launch_bounds__(256, 2)
void layer_gemm_kernel(const ushort* __restrict__ hbf, const ushort* __restrict__ neigh,
                       const ushort* __restrict__ Bt,
                       const float* __restrict__ bias,
                       float* __restrict__ acc, int relu) {
    __shared__ __align__(16) ushort As[128][72];
    __shared__ __align__(16) ushort Bs[128][72];
    const int tid  = threadIdx.x;
    const int wave = tid >> 6, lane = tid & 63;
    const int wm = wave & 1, wn = wave >> 1;
    const int lrow = lane & 15, quad = lane >> 4;
    const int m0 = blockIdx.x * 128;
    const int ldrow = tid >> 3;
    const int ldcol = (tid & 7) * 8;

    floatx4 tot[4][4];
    #pragma unroll
    for (int a = 0; a < 4; ++a)
        #pragma unroll
        for (int b = 0; b < 4; ++b)
            tot[a][b] = (floatx4){0.f, 0.f, 0.f, 0.f};

    for (int k = 0; k < KE; ++k) {
        floatx4 o[4][4];
        #pragma unroll
        for (int a = 0; a < 4; ++a)
            #pragma unroll
            for (int b = 0; b < 4; ++b)
                o[a][b] = (floatx4){0.f, 0.f, 0.f, 0.f};

        for (int part = 0; part < 2; ++part) {
            const ushort* Asrc = part ? (neigh + (size_t)k * NNP * D) : hbf;
            #pragma unroll
            for (int kc = 0; kc < 2; ++kc) {
                __syncthreads();
                const int kbase = kc * 64;
                #pragma unroll
                for (int p = 0; p < 4; ++p) {
                    int r = p * 32 + ldrow;
                    uint4 v = *(const uint4*)(Asrc + (size_t)(m0 + r) * D + kbase + ldcol);
                    *(uint4*)(&As[r][ldcol]) = v;
                }
                const ushort* Bsrc = Bt + (size_t)k * 128 * 256 + part * 128 + kbase;
                #pragma unroll
                for (int p = 0; p < 4; ++p) {
                    int n = p * 32 + ldrow;
                    uint4 v = *(const uint4*)(Bsrc + (size_t)n * 256 + ldcol);
                    *(uint4*)(&Bs[n][ldcol]) = v;
                }
                __syncthreads();
                #pragma unroll
                for (int ks = 0; ks < 2; ++ks) {
                    short8 af[4], bfr[4];
                    const int koff = ks * 32 + quad * 8;
                    #pragma unroll
                    for (int im = 0; im < 4; ++im)
                        af[im] = *(const short8*)(&As[wm * 64 + im * 16 + lrow][koff]);
                    #pragma unroll
                    for (int in = 0; in < 4; ++in)
                        bfr[in] = *(const short8*)(&Bs[wn * 64 + in * 16 + lrow][koff]);
                    #pragma unroll
                    for (int im = 0; im < 4; ++im)
                        #pragma unroll
                        for (int in = 0; in < 4; ++in)
                            o[im][in] = __builtin_amdgcn_mfma_f32_16x16x32_bf16(
                                af[im], bfr[in], o[im][in], 0, 0, 0);
                }
            }
        }
        const float* bk = bias + k * D;
        float bv[4];
        #pragma unroll
        for (int in = 0; in < 4; ++in) bv[in] = bk[wn * 64 + in * 16 + lrow];
        #pragma unroll
        for (int im = 0; im < 4; ++im)
            #pragma unroll
            for (int in = 0; in < 4; ++in)
                #pragma unroll
                for (int r = 0; r < 4; ++r) {
                    float v = o[im][in][r] + bv[in];
                    if (relu) v = fmaxf(v, 0.f);
                    tot[im][in][r] += v;
                }
    }
    #pragma unroll
    for (int im = 0; im < 4; ++im)
        #pragma unroll
        for (int r = 0; r < 4; ++r) {
            int row = m0 + wm * 64 + im * 16 + quad * 4 + r;
            if (row < NN) {
                #pragma unroll
                for (int in = 0; in < 4; ++in)
                    acc[(size_t)row * D + wn * 64 + in * 16 + lrow] = tot[im][in][r];
            }
        }
}

// ---- batchnorm ----
__global__ void stats_kernel(const float* __restrict__ acc,
                             float* __restrict__ colsum, float* __restrict__ colsq) {
    const int c = threadIdx.x;  // 128
    float s = 0.f, s2 = 0.f;
    for (int r = blockIdx.x; r < NN; r += gridDim.x) {
        float v = acc[(size_t)r * D + c];
        s += v; s2 += v * v;
    }
    atomic_add_f32(&colsum[c], s);
    atomic_add_f32(&colsq[c], s2);
}
__global__ void finalize_kernel(const float* __restrict__ colsum, const float* __restrict__ colsq,
                                const float* __restrict__ gamma, const float* __restrict__ beta,
                                float* __restrict__ ss) {
    int c = threadIdx.x;  // 128
    float mu  = colsum[c] * (1.0f / NN);
    float var = colsq[c] * (1.0f / NN) - mu * mu;
    float sc  = gamma[c] * rsqrtf(var + EPS);
    ss[c]     = sc;
    ss[D + c] = beta[c] - mu * sc;
}
__global__ void bn_kernel(const float* __restrict__ acc, const float* __restrict__ ss,
                          ushort* __restrict__ hbf, float* __restrict__ out, int last) {
    size_t i = (size_t)blockIdx.x * blockDim.x + threadIdx.x;
    if (i >= (size_t)NN * D / 4) return;
    int c4 = (int)(i & 31) << 2;
    float4 v  = *(const float4*)(acc + i * 4);
    float4 sc = *(const float4*)(ss + c4);
    float4 sh = *(const float4*)(ss + D + c4);
    float4 o;
    o.x = v.x * sc.x + sh.x;
    o.y = v.y * sc.y + sh.y;
    o.z = v.z * sc.z + sh.z;
    o.w = v.w * sc.w + sh.w;
    if (last) {
        *(float4*)(out + i * 4) = o;
    } else {
        uint2 p;
        p.x = pack2(o.x, o.y);
        p.y = pack2(o.z, o.w);
        *(uint2*)(hbf + i * 4) = p;
    }
}

extern "C" void kernel_launch(void* const* d_in, const int* in_sizes, int n_in,
                              void* d_out, int out_size, void* d_ws, size_t ws_size,
                              hipStream_t stream) {
    const float* x       = (const float*)d_in[0];
    const int*   src     = (const int*)d_in[1];
    const int*   dst     = (const int*)d_in[2];
    const float* W_self  = (const float*)d_in[3];
    const float* W_neigh = (const float*)d_in[4];
    const float* bvec    = (const float*)d_in[5];
    const float* gamma   = (const float*)d_in[6];
    const float* beta    = (const float*)d_in[7];
    float* out = (float*)d_out;

    // ---- workspace layout ----
    float*  acc    = (float*)d_ws;                        // NN*D fp32
    float*  invdeg = acc + (size_t)NN * D;                // KE*NN
    float*  colsum = invdeg + (size_t)KE * NN;            // D
    float*  colsq  = colsum + D;                          // D
    float*  ss     = colsq + D;                           // 2*D
    ushort* hbf    = (ushort*)(ss + 2 * D);               // NNP*D bf16
    ushort* neigh  = hbf + (size_t)NNP * D;               // KE*NNP*D bf16
    ushort* Btw    = neigh + (size_t)KE * NNP * D;        // NL*KE*128*256 bf16
    int*    degi   = (int*)(Btw + (size_t)NL * KE * 128 * 256);  // KE*NN
    int*    rowptr = degi + (size_t)KE * NN;              // KE*(NN+1)
    int*    cursor = rowptr + (size_t)KE * (NN + 1);      // KE*NN
    int*    csr    = cursor + (size_t)KE * NN;            // KE*NE
    int*    bsum   = csr + (size_t)KE * NE;               // KE*NB

    convert_x_kernel<<<(int)(((size_t)NN * D / 4 + 255) / 256), 256, 0, stream>>>(x, hbf);
    wprep_kernel<<<(NL * KE * 128 * 256 + 255) / 256, 256, 0, stream>>>(W_self, W_neigh, Btw);

    hipMemsetAsync(degi, 0, sizeof(int) * (size_t)KE * NN, stream);
    degi_kernel<<<(KE * NE + 255) / 256, 256, 0, stream>>>(dst, degi);
    scan_a_kernel<<<KE * NB, 256, 0, stream>>>(degi, bsum);
    scan_b_kernel<<<KE, 512, 0, stream>>>(bsum);
    scan_c_kernel<<<KE * NB, 256, 0, stream>>>(degi, bsum, rowptr, cursor, invdeg);
    fill_kernel<<<(KE * NE + 255) / 256, 256, 0, stream>>>(src, dst, cursor, csr);

    for (int l = 0; l < NL; ++l) {
        int relu = (l < NL - 1) ? 1 : 0;
        gather3_kernel<<<(KE * NN + 15) / 16, 256, 0, stream>>>(hbf, csr, rowptr, invdeg, neigh);
        layer_gemm_kernel<<<NNP / 128, 256, 0, stream>>>(
            hbf, neigh,
            Btw + (size_t)l * KE * 128 * 256,
            bvec + (size_t)l * KE * D,
            acc, relu);
        hipMemsetAsync(colsum, 0, sizeof(float) * 2 * D, stream);
        stats_kernel<<<512, 128, 0, stream>>>(acc, colsum, colsq);
        finalize_kernel<<<1, 128, 0, stream>>>(colsum, colsq, gamma + (size_t)l * D,
                                               beta + (size_t)l * D, ss);
        bn_kernel<<<(int)(((size_t)NN * D / 4 + 255) / 256), 256, 0, stream>>>(
            acc, ss, hbf, out, (l == NL - 1) ? 1 : 0);
    }
}

// Round 5
// 770.938 us; speedup vs baseline: 15.2672x; 1.1784x over previous
//
#include <hip/hip_runtime.h>

#define NN 100000
#define NNP 100096   // NN padded to multiple of 128 (GEMM tail reads)
#define NE 600000
#define KE 3
#define NL 3
#define D  128
#define EPS 1e-5f
#define NB 391       // ceil(NN/256) blocks per etype for the scan
#define NBKT 196     // buckets per etype: dst>>9 (512 nodes/bucket)
#define EPB 4096     // edges per block in bucket passes
#define NEB 147      // ceil(NE/EPB)

typedef __attribute__((ext_vector_type(8))) short short8;
typedef __attribute__((ext_vector_type(4))) float floatx4;

__device__ __forceinline__ void atomic_add_f32(float* p, float v) { unsafeAtomicAdd(p, v); }

__device__ __forceinline__ float bf2f(unsigned int u16) {
    unsigned int v = u16 << 16;
    return __builtin_bit_cast(float, v);
}
__device__ __forceinline__ unsigned int f2bf(float f) {   // RNE
    unsigned int u = __builtin_bit_cast(unsigned int, f);
    u += 0x7FFFu + ((u >> 16) & 1u);
    return u >> 16;
}
__device__ __forceinline__ unsigned int pack2(float a, float b) {
    return f2bf(a) | (f2bf(b) << 16);
}

// ---- x (fp32) -> h (bf16) ----
__global__ void convert_x_kernel(const float* __restrict__ x, ushort* __restrict__ hbf) {
    size_t i = (size_t)blockIdx.x * blockDim.x + threadIdx.x;
    if (i >= (size_t)NN * D / 4) return;
    float4 v = *(const float4*)(x + i * 4);
    uint2 o;
    o.x = pack2(v.x, v.y);
    o.y = pack2(v.z, v.w);
    *(uint2*)(hbf + i * 4) = o;
}

// ---- W prep: Bt[l,k][n][kk] bf16 ----
__global__ void wprep_kernel(const float* __restrict__ Ws, const float* __restrict__ Wn,
                             ushort* __restrict__ Bt) {
    int idx = blockIdx.x * blockDim.x + threadIdx.x;
    if (idx >= NL * KE * 128 * 256) return;
    int lk  = idx >> 15;
    int rem = idx & 32767;
    int n   = rem >> 8;
    int kk  = rem & 255;
    float v = (kk < 128) ? Ws[(size_t)lk * 16384 + kk * 128 + n]
                         : Wn[(size_t)lk * 16384 + (kk - 128) * 128 + n];
    Bt[idx] = (ushort)f2bf(v);
}

// ==== CSR build: two-level bucket sort ====

// K1: per-block bucket histogram + base reservation
__global__ void bucket_count_kernel(const int* __restrict__ dst,
                                    int* __restrict__ bucketTotal, int* __restrict__ blockBase) {
    const int blk = blockIdx.x;               // KE*NEB
    const int k = blk / NEB, cb = blk - k * NEB;
    __shared__ int hist[NBKT];
    for (int i = threadIdx.x; i < NBKT; i += 256) hist[i] = 0;
    __syncthreads();
    const int e0 = cb * EPB, e1 = min(e0 + EPB, NE);
    for (int e = e0 + threadIdx.x; e < e1; e += 256)
        atomicAdd(&hist[dst[(size_t)k * NE + e] >> 9], 1);
    __syncthreads();
    for (int i = threadIdx.x; i < NBKT; i += 256) {
        int c = hist[i];
        int base = c ? atomicAdd(&bucketTotal[k * NBKT + i], c) : 0;
        blockBase[(size_t)blk * NBKT + i] = base;
    }
}

// K2: exclusive scan of KE*NBKT bucket totals -> global edge offsets
__global__ void bucket_scan_kernel(const int* __restrict__ bucketTotal,
                                   int* __restrict__ bucketStart) {
    __shared__ int sd[1024];
    const int t = threadIdx.x;
    int v = (t < KE * NBKT) ? bucketTotal[t] : 0;
    sd[t] = v;
    __syncthreads();
    for (int off = 1; off < 1024; off <<= 1) {
        int u = (t >= off) ? sd[t - off] : 0;
        __syncthreads();
        sd[t] += u;
        __syncthreads();
    }
    if (t < KE * NBKT) bucketStart[t] = sd[t] - v;
}

// K3: LDS counting-sort the block's edges by bucket, write coalesced runs to ebuf
__global__ void bucket_scatter_kernel(const int* __restrict__ src, const int* __restrict__ dst,
                                      const int* __restrict__ bucketStart,
                                      const int* __restrict__ blockBase,
                                      uint2* __restrict__ ebuf) {
    const int blk = blockIdx.x;
    const int k = blk / NEB, cb = blk - k * NEB;
    __shared__ int hist[NBKT], binoff[NBKT], cur[NBKT];
    __shared__ int sc[256];
    __shared__ uint2 stage[EPB];
    const int t = threadIdx.x;
    for (int i = t; i < NBKT; i += 256) hist[i] = 0;
    __syncthreads();
    const int e0 = cb * EPB, e1 = min(e0 + EPB, NE);
    for (int e = e0 + t; e < e1; e += 256)
        atomicAdd(&hist[dst[(size_t)k * NE + e] >> 9], 1);
    __syncthreads();
    int hv = (t < NBKT) ? hist[t] : 0;
    sc[t] = hv;
    __syncthreads();
    for (int off = 1; off < 256; off <<= 1) {
        int u = (t >= off) ? sc[t - off] : 0;
        __syncthreads();
        sc[t] += u;
        __syncthreads();
    }
    if (t < NBKT) { binoff[t] = sc[t] - hv; cur[t] = sc[t] - hv; }
    __syncthreads();
    for (int e = e0 + t; e < e1; e += 256) {
        int d = dst[(size_t)k * NE + e], s = src[(size_t)k * NE + e];
        int b = d >> 9;
        int p = atomicAdd(&cur[b], 1);
        stage[p] = make_uint2((unsigned)s, (unsigned)d);
    }
    __syncthreads();
    const int n = e1 - e0;
    for (int i = t; i < n; i += 256) {
        uint2 ed = stage[i];
        int b = (int)(ed.y >> 9);
        int pos = bucketStart[k * NBKT + b] + blockBase[(size_t)blk * NBKT + b] + (i - binoff[b]);
        ebuf[pos] = ed;
    }
}

// K4: per-bucket degree histogram -> coalesced degi
__global__ void bucket_deg_kernel(const uint2* __restrict__ ebuf,
                                  const int* __restrict__ bucketStart, int* __restrict__ degi) {
    const int blk = blockIdx.x;               // KE*NBKT
    const int k = blk / NBKT, b = blk - k * NBKT;
    __shared__ int cnt[512];
    for (int i = threadIdx.x; i < 512; i += 256) cnt[i] = 0;
    __syncthreads();
    const int s0 = bucketStart[blk];
    const int s1 = (blk + 1 < KE * NBKT) ? bucketStart[blk + 1] : KE * NE;
    for (int e = s0 + threadIdx.x; e < s1; e += 256)
        atomicAdd(&cnt[ebuf[e].y & 511], 1);
    __syncthreads();
    const int n0 = b << 9;
    for (int i = threadIdx.x; i < 512; i += 256) {
        int node = n0 + i;
        if (node < NN) degi[(size_t)k * NN + node] = cnt[i];
    }
}

// scan phase A: per-256-chunk sums
__global__ void scan_a_kernel(const int* __restrict__ degi, int* __restrict__ bsum) {
    const int b = blockIdx.x;
    const int k = b / NB, lb = b - k * NB;
    const int t = threadIdx.x;
    const int i = lb * 256 + t;
    int deg = (i < NN) ? degi[(size_t)k * NN + i] : 0;
    __shared__ int sd[256];
    sd[t] = deg;
    __syncthreads();
    for (int off = 128; off > 0; off >>= 1) {
        if (t < off) sd[t] += sd[t + off];
        __syncthreads();
    }
    if (t == 0) bsum[b] = sd[0];
}

// scan phase B: per-etype exclusive scan of NB block sums
__global__ void scan_b_kernel(int* __restrict__ bsum) {
    const int k = blockIdx.x;
    const int t = threadIdx.x;          // 512
    int v = (t < NB) ? bsum[k * NB + t] : 0;
    __shared__ int sd[512];
    sd[t] = v;
    __syncthreads();
    for (int off = 1; off < 512; off <<= 1) {
        int u = (t >= off) ? sd[t - off] : 0;
        __syncthreads();
        sd[t] += u;
        __syncthreads();
    }
    if (t < NB) bsum[k * NB + t] = sd[t] - v;
}

// scan phase C: rowptr + invdeg
__global__ void scan_c_kernel(const int* __restrict__ degi, const int* __restrict__ bsum,
                              int* __restrict__ rowptr, float* __restrict__ invdeg) {
    const int b = blockIdx.x;
    const int k = b / NB, lb = b - k * NB;
    const int t = threadIdx.x;
    const int i = lb * 256 + t;
    int deg = (i < NN) ? degi[(size_t)k * NN + i] : 0;
    __shared__ int sd[256];
    sd[t] = deg;
    __syncthreads();
    for (int off = 1; off < 256; off <<= 1) {
        int u = (t >= off) ? sd[t - off] : 0;
        __syncthreads();
        sd[t] += u;
        __syncthreads();
    }
    int val = bsum[b] + sd[t] - deg;
    if (i < NN) {
        rowptr[(size_t)k * (NN + 1) + i] = val;
        invdeg[(size_t)k * NN + i] = 1.0f / (float)max(deg, 1);
    }
    if (i == NN) rowptr[(size_t)k * (NN + 1) + NN] = NE;
}

// K5: per-bucket fill with LDS cursors -> block-local contiguous csr writes
__global__ void bucket_fill_kernel(const uint2* __restrict__ ebuf,
                                   const int* __restrict__ bucketStart,
                                   const int* __restrict__ rowptr, int* __restrict__ csr) {
    const int blk = blockIdx.x;
    const int k = blk / NBKT, b = blk - k * NBKT;
    __shared__ int cur[512];
    const int n0 = b << 9;
    for (int i = threadIdx.x; i < 512; i += 256) {
        int node = n0 + i;
        cur[i] = (node < NN) ? rowptr[(size_t)k * (NN + 1) + node] : 0;
    }
    __syncthreads();
    const int s0 = bucketStart[blk];
    const int s1 = (blk + 1 < KE * NBKT) ? bucketStart[blk + 1] : KE * NE;
    for (int e = s0 + threadIdx.x; e < s1; e += 256) {
        uint2 ed = ebuf[e];
        int p = atomicAdd(&cur[ed.y & 511], 1);
        csr[(size_t)k * NE + p] = (int)ed.x;
    }
}

// ---- gather (all 3 etypes), 16 lanes/node, 2 edges in flight ----
__global__ void gather3_kernel(const ushort* __restrict__ hbf, const int* __restrict__ csr,
                               const int* __restrict__ rowptr, const float* __restrict__ invdeg,
                               ushort* __restrict__ neigh) {
    int g = blockIdx.x * 16 + (threadIdx.x >> 4);
    if (g >= KE * NN) return;
    int k = g / NN, node = g - k * NN;
    const int q = (threadIdx.x & 15) * 8;
    const int* rp = rowptr + (size_t)k * (NN + 1) + node;
    const int* cs = csr + (size_t)k * NE;
    int beg = rp[0], end = rp[1];
    float f0=0,f1=0,f2=0,f3=0,f4=0,f5=0,f6=0,f7=0;
    int j = beg;
    for (; j + 2 <= end; j += 2) {
        int s0 = cs[j], s1 = cs[j + 1];
        uint4 a = *(const uint4*)(hbf + (size_t)s0 * D + q);
        uint4 b = *(const uint4*)(hbf + (size_t)s1 * D + q);
        f0 += bf2f(a.x & 0xffff) + bf2f(b.x & 0xffff);
        f1 += bf2f(a.x >> 16)    + bf2f(b.x >> 16);
        f2 += bf2f(a.y & 0xffff) + bf2f(b.y & 0xffff);
        f3 += bf2f(a.y >> 16)    + bf2f(b.y >> 16);
        f4 += bf2f(a.z & 0xffff) + bf2f(b.z & 0xffff);
        f5 += bf2f(a.z >> 16)    + bf2f(b.z >> 16);
        f6 += bf2f(a.w & 0xffff) + bf2f(b.w & 0xffff);
        f7 += bf2f(a.w >> 16)    + bf2f(b.w >> 16);
    }
    if (j < end) {
        int s0 = cs[j];
        uint4 a = *(const uint4*)(hbf + (size_t)s0 * D + q);
        f0 += bf2f(a.x & 0xffff); f1 += bf2f(a.x >> 16);
        f2 += bf2f(a.y & 0xffff); f3 += bf2f(a.y >> 16);
        f4 += bf2f(a.z & 0xffff); f5 += bf2f(a.z >> 16);
        f6 += bf2f(a.w & 0xffff); f7 += bf2f(a.w >> 16);
    }
    float sc = invdeg[g];
    uint4 o;
    o.x = pack2(f0 * sc, f1 * sc);
    o.y = pack2(f2 * sc, f3 * sc);
    o.z = pack2(f4 * sc, f5 * sc);
    o.w = pack2(f6 * sc, f7 * sc);
    *(uint4*)(neigh + (size_t)k * NNP * D + (size_t)node * D + q) = o;
}

// ---- fused layer GEMM ----
__global__ __launch_bounds__(256, 2)
void layer_gemm_kernel(const ushort* __restrict__ hbf, const ushort* __restrict__ neigh,
                       const ushort* __restrict__ Bt,
                       const float* __restrict__ bias,
                       float* __restrict__ acc, int relu) {
    __shared__ __align__(16) ushort As[128][72];
    __shared__ __align__(16) ushort Bs[128][72];
    const int tid  = threadIdx.x;
    const int wave = tid >> 6, lane = tid & 63;
    const int wm = wave & 1, wn = wave >> 1;
    const int lrow = lane & 15, quad = lane >> 4;
    const int m0 = blockIdx.x * 128;
    const int ldrow = tid >> 3;
    const int ldcol = (tid & 7) * 8;

    floatx4 tot[4][4];
    #pragma unroll
    for (int a = 0; a < 4; ++a)
        #pragma unroll
        for (int b = 0; b < 4; ++b)
            tot[a][b] = (floatx4){0.f, 0.f, 0.f, 0.f};

    for (int k = 0; k < KE; ++k) {
        floatx4 o[4][4];
        #pragma unroll
        for (int a = 0; a < 4; ++a)
            #pragma unroll
            for (int b = 0; b < 4; ++b)
                o[a][b] = (floatx4){0.f, 0.f, 0.f, 0.f};

        for (int part = 0; part < 2; ++part) {
            const ushort* Asrc = part ? (neigh + (size_t)k * NNP * D) : hbf;
            #pragma unroll
            for (int kc = 0; kc < 2; ++kc) {
                __syncthreads();
                const int kbase = kc * 64;
                #pragma unroll
                for (int p = 0; p < 4; ++p) {
                    int r = p * 32 + ldrow;
                    uint4 v = *(const uint4*)(Asrc + (size_t)(m0 + r) * D + kbase + ldcol);
                    *(uint4*)(&As[r][ldcol]) = v;
                }
                const ushort* Bsrc = Bt + (size_t)k * 128 * 256 + part * 128 + kbase;
                #pragma unroll
                for (int p = 0; p < 4; ++p) {
                    int n = p * 32 + ldrow;
                    uint4 v = *(const uint4*)(Bsrc + (size_t)n * 256 + ldcol);
                    *(uint4*)(&Bs[n][ldcol]) = v;
                }
                __syncthreads();
                #pragma unroll
                for (int ks = 0; ks < 2; ++ks) {
                    short8 af[4], bfr[4];
                    const int koff = ks * 32 + quad * 8;
                    #pragma unroll
                    for (int im = 0; im < 4; ++im)
                        af[im] = *(const short8*)(&As[wm * 64 + im * 16 + lrow][koff]);
                    #pragma unroll
                    for (int in = 0; in < 4; ++in)
                        bfr[in] = *(const short8*)(&Bs[wn * 64 + in * 16 + lrow][koff]);
                    #pragma unroll
                    for (int im = 0; im < 4; ++im)
                        #pragma unroll
                        for (int in = 0; in < 4; ++in)
                            o[im][in] = __builtin_amdgcn_mfma_f32_16x16x32_bf16(
                                af[im], bfr[in], o[im][in], 0, 0, 0);
                }
            }
        }
        const float* bk = bias + k * D;
        float bv[4];
        #pragma unroll
        for (int in = 0; in < 4; ++in) bv[in] = bk[wn * 64 + in * 16 + lrow];
        #pragma unroll
        for (int im = 0; im < 4; ++im)
            #pragma unroll
            for (int in = 0; in < 4; ++in)
                #pragma unroll
                for (int r = 0; r < 4; ++r) {
                    float v = o[im][in][r] + bv[in];
                    if (relu) v = fmaxf(v, 0.f);
                    tot[im][in][r] += v;
                }
    }
    #pragma unroll
    for (int im = 0; im < 4; ++im)
        #pragma unroll
        for (int r = 0; r < 4; ++r) {
            int row = m0 + wm * 64 + im * 16 + quad * 4 + r;
            if (row < NN) {
                #pragma unroll
                for (int in = 0; in < 4; ++in)
                    acc[(size_t)row * D + wn * 64 + in * 16 + lrow] = tot[im][in][r];
            }
        }
}

// ---- batchnorm ----
__global__ void stats_kernel(const float* __restrict__ acc,
                             float* __restrict__ colsum, float* __restrict__ colsq) {
    const int c = threadIdx.x;  // 128
    float s = 0.f, s2 = 0.f;
    for (int r = blockIdx.x; r < NN; r += gridDim.x) {
        float v = acc[(size_t)r * D + c];
        s += v; s2 += v * v;
    }
    atomic_add_f32(&colsum[c], s);
    atomic_add_f32(&colsq[c], s2);
}
__global__ void finalize_kernel(const float* __restrict__ colsum, const float* __restrict__ colsq,
                                const float* __restrict__ gamma, const float* __restrict__ beta,
                                float* __restrict__ ss) {
    int c = threadIdx.x;  // 128
    float mu  = colsum[c] * (1.0f / NN);
    float var = colsq[c] * (1.0f / NN) - mu * mu;
    float sc  = gamma[c] * rsqrtf(var + EPS);
    ss[c]     = sc;
    ss[D + c] = beta[c] - mu * sc;
}
__global__ void bn_kernel(const float* __restrict__ acc, const float* __restrict__ ss,
                          ushort* __restrict__ hbf, float* __restrict__ out, int last) {
    size_t i = (size_t)blockIdx.x * blockDim.x + threadIdx.x;
    if (i >= (size_t)NN * D / 4) return;
    int c4 = (int)(i & 31) << 2;
    float4 v  = *(const float4*)(acc + i * 4);
    float4 sc = *(const float4*)(ss + c4);
    float4 sh = *(const float4*)(ss + D + c4);
    float4 o;
    o.x = v.x * sc.x + sh.x;
    o.y = v.y * sc.y + sh.y;
    o.z = v.z * sc.z + sh.z;
    o.w = v.w * sc.w + sh.w;
    if (last) {
        *(float4*)(out + i * 4) = o;
    } else {
        uint2 p;
        p.x = pack2(o.x, o.y);
        p.y = pack2(o.z, o.w);
        *(uint2*)(hbf + i * 4) = p;
    }
}

extern "C" void kernel_launch(void* const* d_in, const int* in_sizes, int n_in,
                              void* d_out, int out_size, void* d_ws, size_t ws_size,
                              hipStream_t stream) {
    const float* x       = (const float*)d_in[0];
    const int*   src     = (const int*)d_in[1];
    const int*   dst     = (const int*)d_in[2];
    const float* W_self  = (const float*)d_in[3];
    const float* W_neigh = (const float*)d_in[4];
    const float* bvec    = (const float*)d_in[5];
    const float* gamma   = (const float*)d_in[6];
    const float* beta    = (const float*)d_in[7];
    float* out = (float*)d_out;

    // ---- workspace layout ----
    float*  acc    = (float*)d_ws;                        // NN*D fp32
    float*  invdeg = acc + (size_t)NN * D;                // KE*NN
    float*  colsum = invdeg + (size_t)KE * NN;            // D
    float*  colsq  = colsum + D;                          // D
    float*  ss     = colsq + D;                           // 2*D
    ushort* hbf    = (ushort*)(ss + 2 * D);               // NNP*D bf16
    ushort* neigh  = hbf + (size_t)NNP * D;               // KE*NNP*D bf16
    ushort* Btw    = neigh + (size_t)KE * NNP * D;        // NL*KE*128*256 bf16
    int*    degi   = (int*)(Btw + (size_t)NL * KE * 128 * 256);  // KE*NN
    int*    rowptr = degi + (size_t)KE * NN;              // KE*(NN+1)
    int*    csr    = rowptr + (size_t)KE * (NN + 1);      // KE*NE
    int*    bsum   = csr + (size_t)KE * NE;               // KE*NB
    int*    bucketTotal = bsum + (size_t)KE * NB;         // KE*NBKT
    int*    bucketStart = bucketTotal + KE * NBKT;        // KE*NBKT
    int*    blockBase   = bucketStart + KE * NBKT;        // KE*NEB*NBKT
    uint2*  ebuf   = (uint2*)acc;   // aliases acc (14.4MB <= 51.2MB); CSR build fully precedes layer loop

    convert_x_kernel<<<(int)(((size_t)NN * D / 4 + 255) / 256), 256, 0, stream>>>(x, hbf);
    wprep_kernel<<<(NL * KE * 128 * 256 + 255) / 256, 256, 0, stream>>>(W_self, W_neigh, Btw);

    hipMemsetAsync(bucketTotal, 0, sizeof(int) * KE * NBKT, stream);
    bucket_count_kernel<<<KE * NEB, 256, 0, stream>>>(dst, bucketTotal, blockBase);
    bucket_scan_kernel<<<1, 1024, 0, stream>>>(bucketTotal, bucketStart);
    bucket_scatter_kernel<<<KE * NEB, 256, 0, stream>>>(src, dst, bucketStart, blockBase, ebuf);
    bucket_deg_kernel<<<KE * NBKT, 256, 0, stream>>>(ebuf, bucketStart, degi);
    scan_a_kernel<<<KE * NB, 256, 0, stream>>>(degi, bsum);
    scan_b_kernel<<<KE, 512, 0, stream>>>(bsum);
    scan_c_kernel<<<KE * NB, 256, 0, stream>>>(degi, bsum, rowptr, invdeg);
    bucket_fill_kernel<<<KE * NBKT, 256, 0, stream>>>(ebuf, bucketStart, rowptr, csr);

    for (int l = 0; l < NL; ++l) {
        int relu = (l < NL - 1) ? 1 : 0;
        gather3_kernel<<<(KE * NN + 15) / 16, 256, 0, stream>>>(hbf, csr, rowptr, invdeg, neigh);
        layer_gemm_kernel<<<NNP / 128, 256, 0, stream>>>(
            hbf, neigh,
            Btw + (size_t)l * KE * 128 * 256,
            bvec + (size_t)l * KE * D,
            acc, relu);
        hipMemsetAsync(colsum, 0, sizeof(float) * 2 * D, stream);
        stats_kernel<<<512, 128, 0, stream>>>(acc, colsum, colsq);
        finalize_kernel<<<1, 128, 0, stream>>>(colsum, colsq, gamma + (size_t)l * D,
                                               beta + (size_t)l * D, ss);
        bn_kernel<<<(int)(((size_t)NN * D / 4 + 255) / 256), 256, 0, stream>>>(
            acc, ss, hbf, out, (l == NL - 1) ? 1 : 0);
    }
}

// Round 7
// 591.072 us; speedup vs baseline: 19.9131x; 1.3043x over previous
//
#include <hip/hip_runtime.h>

#define NN 100000
#define NNP 100096   // NN padded to multiple of 128 (GEMM tail reads)
#define NE 600000
#define KE 3
#define NL 3
#define D  128
#define EPS 1e-5f
#define NB 391       // ceil(NN/256) blocks per etype for the scan
#define NBKT 196     // buckets per etype: dst>>9 (512 nodes/bucket)
#define EPB 4096     // edges per block in bucket passes
#define NEB 147      // ceil(NE/EPB)
#define NSL 16       // stat slices (atomic contention spread)

typedef __attribute__((ext_vector_type(8))) short short8;
typedef __attribute__((ext_vector_type(4))) float floatx4;

__device__ __forceinline__ void atomic_add_f32(float* p, float v) { unsafeAtomicAdd(p, v); }

__device__ __forceinline__ float bf2f(unsigned int u16) {
    unsigned int v = u16 << 16;
    return __builtin_bit_cast(float, v);
}
__device__ __forceinline__ unsigned int f2bf(float f) {   // RNE
    unsigned int u = __builtin_bit_cast(unsigned int, f);
    u += 0x7FFFu + ((u >> 16) & 1u);
    return u >> 16;
}
__device__ __forceinline__ unsigned int pack2(float a, float b) {
    return f2bf(a) | (f2bf(b) << 16);
}

// ---- x (fp32) -> h (bf16) ----
__global__ void convert_x_kernel(const float* __restrict__ x, ushort* __restrict__ hbf) {
    size_t i = (size_t)blockIdx.x * blockDim.x + threadIdx.x;
    if (i >= (size_t)NN * D / 4) return;
    float4 v = *(const float4*)(x + i * 4);
    uint2 o;
    o.x = pack2(v.x, v.y);
    o.y = pack2(v.z, v.w);
    *(uint2*)(hbf + i * 4) = o;
}

// ---- W prep: Bt[l,k][n][kk] bf16 ----
__global__ void wprep_kernel(const float* __restrict__ Ws, const float* __restrict__ Wn,
                             ushort* __restrict__ Bt) {
    int idx = blockIdx.x * blockDim.x + threadIdx.x;
    if (idx >= NL * KE * 128 * 256) return;
    int lk  = idx >> 15;
    int rem = idx & 32767;
    int n   = rem >> 8;
    int kk  = rem & 255;
    float v = (kk < 128) ? Ws[(size_t)lk * 16384 + kk * 128 + n]
                         : Wn[(size_t)lk * 16384 + (kk - 128) * 128 + n];
    Bt[idx] = (ushort)f2bf(v);
}

// ==== CSR build: two-level bucket sort ====
__global__ void bucket_count_kernel(const int* __restrict__ dst,
                                    int* __restrict__ bucketTotal, int* __restrict__ blockBase) {
    const int blk = blockIdx.x;               // KE*NEB
    const int k = blk / NEB, cb = blk - k * NEB;
    __shared__ int hist[NBKT];
    for (int i = threadIdx.x; i < NBKT; i += 256) hist[i] = 0;
    __syncthreads();
    const int e0 = cb * EPB, e1 = min(e0 + EPB, NE);
    for (int e = e0 + threadIdx.x; e < e1; e += 256)
        atomicAdd(&hist[dst[(size_t)k * NE + e] >> 9], 1);
    __syncthreads();
    for (int i = threadIdx.x; i < NBKT; i += 256) {
        int c = hist[i];
        int base = c ? atomicAdd(&bucketTotal[k * NBKT + i], c) : 0;
        blockBase[(size_t)blk * NBKT + i] = base;
    }
}

__global__ void bucket_scan_kernel(const int* __restrict__ bucketTotal,
                                   int* __restrict__ bucketStart) {
    __shared__ int sd[1024];
    const int t = threadIdx.x;
    int v = (t < KE * NBKT) ? bucketTotal[t] : 0;
    sd[t] = v;
    __syncthreads();
    for (int off = 1; off < 1024; off <<= 1) {
        int u = (t >= off) ? sd[t - off] : 0;
        __syncthreads();
        sd[t] += u;
        __syncthreads();
    }
    if (t < KE * NBKT) bucketStart[t] = sd[t] - v;
}

__global__ void bucket_scatter_kernel(const int* __restrict__ src, const int* __restrict__ dst,
                                      const int* __restrict__ bucketStart,
                                      const int* __restrict__ blockBase,
                                      uint2* __restrict__ ebuf) {
    const int blk = blockIdx.x;
    const int k = blk / NEB, cb = blk - k * NEB;
    __shared__ int hist[NBKT], binoff[NBKT], cur[NBKT];
    __shared__ int sc[256];
    __shared__ uint2 stage[EPB];
    const int t = threadIdx.x;
    for (int i = t; i < NBKT; i += 256) hist[i] = 0;
    __syncthreads();
    const int e0 = cb * EPB, e1 = min(e0 + EPB, NE);
    for (int e = e0 + t; e < e1; e += 256)
        atomicAdd(&hist[dst[(size_t)k * NE + e] >> 9], 1);
    __syncthreads();
    int hv = (t < NBKT) ? hist[t] : 0;
    sc[t] = hv;
    __syncthreads();
    for (int off = 1; off < 256; off <<= 1) {
        int u = (t >= off) ? sc[t - off] : 0;
        __syncthreads();
        sc[t] += u;
        __syncthreads();
    }
    if (t < NBKT) { binoff[t] = sc[t] - hv; cur[t] = sc[t] - hv; }
    __syncthreads();
    for (int e = e0 + t; e < e1; e += 256) {
        int d = dst[(size_t)k * NE + e], s = src[(size_t)k * NE + e];
        int b = d >> 9;
        int p = atomicAdd(&cur[b], 1);
        stage[p] = make_uint2((unsigned)s, (unsigned)d);
    }
    __syncthreads();
    const int n = e1 - e0;
    for (int i = t; i < n; i += 256) {
        uint2 ed = stage[i];
        int b = (int)(ed.y >> 9);
        int pos = bucketStart[k * NBKT + b] + blockBase[(size_t)blk * NBKT + b] + (i - binoff[b]);
        ebuf[pos] = ed;
    }
}

__global__ void bucket_deg_kernel(const uint2* __restrict__ ebuf,
                                  const int* __restrict__ bucketStart, int* __restrict__ degi) {
    const int blk = blockIdx.x;               // KE*NBKT
    const int k = blk / NBKT, b = blk - k * NBKT;
    __shared__ int cnt[512];
    for (int i = threadIdx.x; i < 512; i += 256) cnt[i] = 0;
    __syncthreads();
    const int s0 = bucketStart[blk];
    const int s1 = (blk + 1 < KE * NBKT) ? bucketStart[blk + 1] : KE * NE;
    for (int e = s0 + threadIdx.x; e < s1; e += 256)
        atomicAdd(&cnt[ebuf[e].y & 511], 1);
    __syncthreads();
    const int n0 = b << 9;
    for (int i = threadIdx.x; i < 512; i += 256) {
        int node = n0 + i;
        if (node < NN) degi[(size_t)k * NN + node] = cnt[i];
    }
}

__global__ void scan_a_kernel(const int* __restrict__ degi, int* __restrict__ bsum) {
    const int b = blockIdx.x;
    const int k = b / NB, lb = b - k * NB;
    const int t = threadIdx.x;
    const int i = lb * 256 + t;
    int deg = (i < NN) ? degi[(size_t)k * NN + i] : 0;
    __shared__ int sd[256];
    sd[t] = deg;
    __syncthreads();
    for (int off = 128; off > 0; off >>= 1) {
        if (t < off) sd[t] += sd[t + off];
        __syncthreads();
    }
    if (t == 0) bsum[b] = sd[0];
}

__global__ void scan_b_kernel(int* __restrict__ bsum) {
    const int k = blockIdx.x;
    const int t = threadIdx.x;          // 512
    int v = (t < NB) ? bsum[k * NB + t] : 0;
    __shared__ int sd[512];
    sd[t] = v;
    __syncthreads();
    for (int off = 1; off < 512; off <<= 1) {
        int u = (t >= off) ? sd[t - off] : 0;
        __syncthreads();
        sd[t] += u;
        __syncthreads();
    }
    if (t < NB) bsum[k * NB + t] = sd[t] - v;
}

__global__ void scan_c_kernel(const int* __restrict__ degi, const int* __restrict__ bsum,
                              int* __restrict__ rowptr, float* __restrict__ invdeg) {
    const int b = blockIdx.x;
    const int k = b / NB, lb = b - k * NB;
    const int t = threadIdx.x;
    const int i = lb * 256 + t;
    int deg = (i < NN) ? degi[(size_t)k * NN + i] : 0;
    __shared__ int sd[256];
    sd[t] = deg;
    __syncthreads();
    for (int off = 1; off < 256; off <<= 1) {
        int u = (t >= off) ? sd[t - off] : 0;
        __syncthreads();
        sd[t] += u;
        __syncthreads();
    }
    int val = bsum[b] + sd[t] - deg;
    if (i < NN) {
        rowptr[(size_t)k * (NN + 1) + i] = val;
        invdeg[(size_t)k * NN + i] = 1.0f / (float)max(deg, 1);
    }
    if (i == NN) rowptr[(size_t)k * (NN + 1) + NN] = NE;
}

__global__ void bucket_fill_kernel(const uint2* __restrict__ ebuf,
                                   const int* __restrict__ bucketStart,
                                   const int* __restrict__ rowptr, int* __restrict__ csr) {
    const int blk = blockIdx.x;
    const int k = blk / NBKT, b = blk - k * NBKT;
    __shared__ int cur[512];
    const int n0 = b << 9;
    for (int i = threadIdx.x; i < 512; i += 256) {
        int node = n0 + i;
        cur[i] = (node < NN) ? rowptr[(size_t)k * (NN + 1) + node] : 0;
    }
    __syncthreads();
    const int s0 = bucketStart[blk];
    const int s1 = (blk + 1 < KE * NBKT) ? bucketStart[blk + 1] : KE * NE;
    for (int e = s0 + threadIdx.x; e < s1; e += 256) {
        uint2 ed = ebuf[e];
        int p = atomicAdd(&cur[ed.y & 511], 1);
        csr[(size_t)k * NE + p] = (int)ed.x;
    }
}

// ---- gather (all 3 etypes), bf16 rows, 16 lanes/node, 4 edges in flight ----
__global__ void gather3_kernel(const ushort* __restrict__ hbf, const int* __restrict__ csr,
                               const int* __restrict__ rowptr, const float* __restrict__ invdeg,
                               ushort* __restrict__ neigh) {
    int g = blockIdx.x * 16 + (threadIdx.x >> 4);
    if (g >= KE * NN) return;
    int k = g / NN, node = g - k * NN;
    const int q = (threadIdx.x & 15) * 8;
    const int* rp = rowptr + (size_t)k * (NN + 1) + node;
    const int* cs = csr + (size_t)k * NE;
    int beg = rp[0], end = rp[1];
    float f0=0,f1=0,f2=0,f3=0,f4=0,f5=0,f6=0,f7=0;
    int j = beg;
    for (; j + 4 <= end; j += 4) {
        int s0 = cs[j], s1 = cs[j + 1], s2 = cs[j + 2], s3 = cs[j + 3];
        uint4 a = *(const uint4*)(hbf + (size_t)s0 * D + q);
        uint4 b = *(const uint4*)(hbf + (size_t)s1 * D + q);
        uint4 c = *(const uint4*)(hbf + (size_t)s2 * D + q);
        uint4 d = *(const uint4*)(hbf + (size_t)s3 * D + q);
        f0 += bf2f(a.x & 0xffff) + bf2f(b.x & 0xffff) + bf2f(c.x & 0xffff) + bf2f(d.x & 0xffff);
        f1 += bf2f(a.x >> 16)    + bf2f(b.x >> 16)    + bf2f(c.x >> 16)    + bf2f(d.x >> 16);
        f2 += bf2f(a.y & 0xffff) + bf2f(b.y & 0xffff) + bf2f(c.y & 0xffff) + bf2f(d.y & 0xffff);
        f3 += bf2f(a.y >> 16)    + bf2f(b.y >> 16)    + bf2f(c.y >> 16)    + bf2f(d.y >> 16);
        f4 += bf2f(a.z & 0xffff) + bf2f(b.z & 0xffff) + bf2f(c.z & 0xffff) + bf2f(d.z & 0xffff);
        f5 += bf2f(a.z >> 16)    + bf2f(b.z >> 16)    + bf2f(c.z >> 16)    + bf2f(d.z >> 16);
        f6 += bf2f(a.w & 0xffff) + bf2f(b.w & 0xffff) + bf2f(c.w & 0xffff) + bf2f(d.w & 0xffff);
        f7 += bf2f(a.w >> 16)    + bf2f(b.w >> 16)    + bf2f(c.w >> 16)    + bf2f(d.w >> 16);
    }
    for (; j < end; ++j) {
        int s0 = cs[j];
        uint4 a = *(const uint4*)(hbf + (size_t)s0 * D + q);
        f0 += bf2f(a.x & 0xffff); f1 += bf2f(a.x >> 16);
        f2 += bf2f(a.y & 0xffff); f3 += bf2f(a.y >> 16);
        f4 += bf2f(a.z & 0xffff); f5 += bf2f(a.z >> 16);
        f6 += bf2f(a.w & 0xffff); f7 += bf2f(a.w >> 16);
    }
    float sc = invdeg[g];
    uint4 o;
    o.x = pack2(f0 * sc, f1 * sc);
    o.y = pack2(f2 * sc, f3 * sc);
    o.z = pack2(f4 * sc, f5 * sc);
    o.w = pack2(f6 * sc, f7 * sc);
    *(uint4*)(neigh + (size_t)k * NNP * D + (size_t)node * D + q) = o;
}

// ---- fused layer GEMM + column stats; acc stored bf16 via LDS staging ----
__global__ __launch_bounds__(256, 2)
void layer_gemm_kernel(const ushort* __restrict__ hbf, const ushort* __restrict__ neigh,
                       const ushort* __restrict__ Bt,
                       const float* __restrict__ bias,
                       ushort* __restrict__ accb, int relu,
                       float* __restrict__ colsum, float* __restrict__ colsq) {
    __shared__ __align__(16) ushort shbuf[2][128][72];   // 36 KB; As/Bs, reused in epilogue
#define As shbuf[0]
#define Bs shbuf[1]
    const int tid  = threadIdx.x;
    const int wave = tid >> 6, lane = tid & 63;
    const int wm = wave & 1, wn = wave >> 1;
    const int lrow = lane & 15, quad = lane >> 4;
    const int m0 = blockIdx.x * 128;
    const int ldrow = tid >> 3;
    const int ldcol = (tid & 7) * 8;

    floatx4 tot[4][4];
    #pragma unroll
    for (int a = 0; a < 4; ++a)
        #pragma unroll
        for (int b = 0; b < 4; ++b)
            tot[a][b] = (floatx4){0.f, 0.f, 0.f, 0.f};

    for (int k = 0; k < KE; ++k) {
        floatx4 o[4][4];
        #pragma unroll
        for (int a = 0; a < 4; ++a)
            #pragma unroll
            for (int b = 0; b < 4; ++b)
                o[a][b] = (floatx4){0.f, 0.f, 0.f, 0.f};

        for (int part = 0; part < 2; ++part) {
            const ushort* Asrc = part ? (neigh + (size_t)k * NNP * D) : hbf;
            #pragma unroll
            for (int kc = 0; kc < 2; ++kc) {
                __syncthreads();
                const int kbase = kc * 64;
                #pragma unroll
                for (int p = 0; p < 4; ++p) {
                    int r = p * 32 + ldrow;
                    uint4 v = *(const uint4*)(Asrc + (size_t)(m0 + r) * D + kbase + ldcol);
                    *(uint4*)(&As[r][ldcol]) = v;
                }
                const ushort* Bsrc = Bt + (size_t)k * 128 * 256 + part * 128 + kbase;
                #pragma unroll
                for (int p = 0; p < 4; ++p) {
                    int n = p * 32 + ldrow;
                    uint4 v = *(const uint4*)(Bsrc + (size_t)n * 256 + ldcol);
                    *(uint4*)(&Bs[n][ldcol]) = v;
                }
                __syncthreads();
                #pragma unroll
                for (int ks = 0; ks < 2; ++ks) {
                    short8 af[4], bfr[4];
                    const int koff = ks * 32 + quad * 8;
                    #pragma unroll
                    for (int im = 0; im < 4; ++im)
                        af[im] = *(const short8*)(&As[wm * 64 + im * 16 + lrow][koff]);
                    #pragma unroll
                    for (int in = 0; in < 4; ++in)
                        bfr[in] = *(const short8*)(&Bs[wn * 64 + in * 16 + lrow][koff]);
                    #pragma unroll
                    for (int im = 0; im < 4; ++im)
                        #pragma unroll
                        for (int in = 0; in < 4; ++in)
                            o[im][in] = __builtin_amdgcn_mfma_f32_16x16x32_bf16(
                                af[im], bfr[in], o[im][in], 0, 0, 0);
                }
            }
        }
        const float* bk = bias + k * D;
        float bv[4];
        #pragma unroll
        for (int in = 0; in < 4; ++in) bv[in] = bk[wn * 64 + in * 16 + lrow];
        #pragma unroll
        for (int im = 0; im < 4; ++im)
            #pragma unroll
            for (int in = 0; in < 4; ++in)
                #pragma unroll
                for (int r = 0; r < 4; ++r) {
                    float v = o[im][in][r] + bv[in];
                    if (relu) v = fmaxf(v, 0.f);
                    tot[im][in][r] += v;
                }
    }

    // ---- fused column stats from fp32 registers (mask tail rows >= NN) ----
    float ls[4] = {0.f, 0.f, 0.f, 0.f}, lq[4] = {0.f, 0.f, 0.f, 0.f};
    #pragma unroll
    for (int im = 0; im < 4; ++im)
        #pragma unroll
        for (int r = 0; r < 4; ++r) {
            int row = m0 + wm * 64 + im * 16 + quad * 4 + r;
            bool ok = row < NN;
            #pragma unroll
            for (int in = 0; in < 4; ++in) {
                float v = ok ? tot[im][in][r] : 0.f;
                ls[in] += v;
                lq[in] += v * v;
            }
        }
    __syncthreads();                                   // MFMA-loop LDS reads done
    float* redS = (float*)&shbuf[0][0][0];             // [128][8] floats
    float* redQ = ((float*)&shbuf[0][0][0]) + 1024;    // [128][8] floats
    #pragma unroll
    for (int in = 0; in < 4; ++in) {
        int col = wn * 64 + in * 16 + lrow;
        int slot = col * 8 + wm * 4 + quad;
        redS[slot] = ls[in];
        redQ[slot] = lq[in];
    }
    __syncthreads();
    if (tid < 128) {
        float s = 0.f, q = 0.f;
        #pragma unroll
        for (int i = 0; i < 8; ++i) { s += redS[tid * 8 + i]; q += redQ[tid * 8 + i]; }
        int slice = blockIdx.x & (NSL - 1);
        atomic_add_f32(&colsum[slice * D + tid], s);
        atomic_add_f32(&colsq[slice * D + tid], q);
    }
    __syncthreads();                                   // reduction reads done before C overwrite

    // ---- C tile -> LDS (bf16) -> coalesced global stores ----
    ushort* Cs = &shbuf[0][0][0];                      // [128][128] ushort = 32 KB (fits in 36 KB)
    #pragma unroll
    for (int im = 0; im < 4; ++im)
        #pragma unroll
        for (int r = 0; r < 4; ++r) {
            int rl = wm * 64 + im * 16 + quad * 4 + r;
            #pragma unroll
            for (int in = 0; in < 4; ++in)
                Cs[rl * 128 + wn * 64 + in * 16 + lrow] = (ushort)f2bf(tot[im][in][r]);
        }
    __syncthreads();
    // 2048 uint4 total; 8 per thread; thread t does chunks t + j*256
    #pragma unroll
    for (int jj = 0; jj < 8; ++jj) {
        int c8 = tid + jj * 256;           // uint4 index
        int rl = c8 >> 4;                  // 16 uint4 per 128-col row
        int cc = (c8 & 15) * 8;
        int row = m0 + rl;
        if (row < NN)
            *(uint4*)(accb + (size_t)row * D + cc) = *(const uint4*)(Cs + rl * 128 + cc);
    }
#undef As
#undef Bs
}

// ---- batchnorm finalize + apply ----
__global__ void finalize_kernel(const float* __restrict__ colsum, const float* __restrict__ colsq,
                                const float* __restrict__ gamma, const float* __restrict__ beta,
                                float* __restrict__ ss) {
    int c = threadIdx.x;  // 128
    float s = 0.f, q = 0.f;
    #pragma unroll
    for (int i = 0; i < NSL; ++i) { s += colsum[i * D + c]; q += colsq[i * D + c]; }
    float mu  = s * (1.0f / NN);
    float var = q * (1.0f / NN) - mu * mu;
    float sc  = gamma[c] * rsqrtf(var + EPS);
    ss[c]     = sc;
    ss[D + c] = beta[c] - mu * sc;
}

__global__ void bn_kernel(const ushort* __restrict__ accb, const float* __restrict__ ss,
                          ushort* __restrict__ hbf, float* __restrict__ out, int last) {
    size_t i = (size_t)blockIdx.x * blockDim.x + threadIdx.x;
    if (i >= (size_t)NN * D / 4) return;
    int c4 = (int)(i & 31) << 2;
    uint2 a = *(const uint2*)(accb + i * 4);
    float4 v = {bf2f(a.x & 0xffff), bf2f(a.x >> 16), bf2f(a.y & 0xffff), bf2f(a.y >> 16)};
    float4 sc = *(const float4*)(ss + c4);
    float4 sh = *(const float4*)(ss + D + c4);
    float4 o;
    o.x = v.x * sc.x + sh.x;
    o.y = v.y * sc.y + sh.y;
    o.z = v.z * sc.z + sh.z;
    o.w = v.w * sc.w + sh.w;
    if (last) {
        *(float4*)(out + i * 4) = o;
    } else {
        uint2 p;
        p.x = pack2(o.x, o.y);
        p.y = pack2(o.z, o.w);
        *(uint2*)(hbf + i * 4) = p;
    }
}

extern "C" void kernel_launch(void* const* d_in, const int* in_sizes, int n_in,
                              void* d_out, int out_size, void* d_ws, size_t ws_size,
                              hipStream_t stream) {
    const float* x       = (const float*)d_in[0];
    const int*   src     = (const int*)d_in[1];
    const int*   dst     = (const int*)d_in[2];
    const float* W_self  = (const float*)d_in[3];
    const float* W_neigh = (const float*)d_in[4];
    const float* bvec    = (const float*)d_in[5];
    const float* gamma   = (const float*)d_in[6];
    const float* beta    = (const float*)d_in[7];
    float* out = (float*)d_out;

    // ---- workspace layout ----
    ushort* accb   = (ushort*)d_ws;                       // NN*D bf16 (26 MB region head)
    float*  invdeg = (float*)(accb + (size_t)NNP * D);    // KE*NN
    float*  colsum = invdeg + (size_t)KE * NN;            // NSL*D
    float*  colsq  = colsum + NSL * D;                    // NSL*D
    float*  ss     = colsq + NSL * D;                     // 2*D
    ushort* hbf    = (ushort*)(ss + 2 * D);               // NNP*D bf16
    ushort* neigh  = hbf + (size_t)NNP * D;               // KE*NNP*D bf16
    ushort* Btw    = neigh + (size_t)KE * NNP * D;        // NL*KE*128*256 bf16
    int*    degi   = (int*)(Btw + (size_t)NL * KE * 128 * 256);  // KE*NN
    int*    rowptr = degi + (size_t)KE * NN;              // KE*(NN+1)
    int*    csr    = rowptr + (size_t)KE * (NN + 1);      // KE*NE
    int*    bsum   = csr + (size_t)KE * NE;               // KE*NB
    int*    bucketTotal = bsum + (size_t)KE * NB;         // KE*NBKT
    int*    bucketStart = bucketTotal + KE * NBKT;        // KE*NBKT
    int*    blockBase   = bucketStart + KE * NBKT;        // KE*NEB*NBKT
    uint2*  ebuf   = (uint2*)accb;  // aliases accb (14.4MB <= 25.6MB); CSR build precedes layer loop

    convert_x_kernel<<<(int)(((size_t)NN * D / 4 + 255) / 256), 256, 0, stream>>>(x, hbf);
    wprep_kernel<<<(NL * KE * 128 * 256 + 255) / 256, 256, 0, stream>>>(W_self, W_neigh, Btw);

    hipMemsetAsync(bucketTotal, 0, sizeof(int) * KE * NBKT, stream);
    bucket_count_kernel<<<KE * NEB, 256, 0, stream>>>(dst, bucketTotal, blockBase);
    bucket_scan_kernel<<<1, 1024, 0, stream>>>(bucketTotal, bucketStart);
    bucket_scatter_kernel<<<KE * NEB, 256, 0, stream>>>(src, dst, bucketStart, blockBase, ebuf);
    bucket_deg_kernel<<<KE * NBKT, 256, 0, stream>>>(ebuf, bucketStart, degi);
    scan_a_kernel<<<KE * NB, 256, 0, stream>>>(degi, bsum);
    scan_b_kernel<<<KE, 512, 0, stream>>>(bsum);
    scan_c_kernel<<<KE * NB, 256, 0, stream>>>(degi, bsum, rowptr, invdeg);
    bucket_fill_kernel<<<KE * NBKT, 256, 0, stream>>>(ebuf, bucketStart, rowptr, csr);

    for (int l = 0; l < NL; ++l) {
        int relu = (l < NL - 1) ? 1 : 0;
        gather3_kernel<<<(KE * NN + 15) / 16, 256, 0, stream>>>(hbf, csr, rowptr, invdeg, neigh);
        hipMemsetAsync(colsum, 0, sizeof(float) * 2 * NSL * D, stream);
        layer_gemm_kernel<<<NNP / 128, 256, 0, stream>>>(
            hbf, neigh,
            Btw + (size_t)l * KE * 128 * 256,
            bvec + (size_t)l * KE * D,
            accb, relu, colsum, colsq);
        finalize_kernel<<<1, 128, 0, stream>>>(colsum, colsq, gamma + (size_t)l * D,
                                               beta + (size_t)l * D, ss);
        bn_kernel<<<(int)(((size_t)NN * D / 4 + 255) / 256), 256, 0, stream>>>(
            accb, ss, hbf, out, (l == NL - 1) ? 1 : 0);
    }
}